// Round 11
// baseline (322.124 us; speedup 1.0000x reference)
//
#include <hip/hip_runtime.h>
#include <hip/hip_bf16.h>
#include <math.h>

typedef unsigned short u16;
typedef __attribute__((ext_vector_type(8))) short s16x8;
typedef __attribute__((ext_vector_type(4))) float f32x4;

#define B_ 4
#define N_ 4096
#define C_ 1024
#define M_ (B_*N_)
#define NT_ 16   // K / 64

__device__ __forceinline__ u16 f2bf(float f) {
  unsigned u = __builtin_bit_cast(unsigned, f);
  u = u + 0x7fffu + ((u >> 16) & 1u);
  return (u16)(u >> 16);
}
__device__ __forceinline__ float bf2f(u16 h) {
  unsigned u = ((unsigned)h) << 16;
  return __builtin_bit_cast(float, u);
}

// ---------------- kernel T: one-time rope trig table (512 pairs) ----------------
__global__ void trig_kernel(float* __restrict__ ctab, float* __restrict__ stab) {
  const int i = threadIdx.x;   // 0..511
  const float theta = powf(10000.f, -(float)i * (1.f/512.f));
  ctab[i] = cosf(theta);
  stab[i] = sinf(theta);
}

// ---------------- kernel 0: fp32 -> bf16 precast of x and W ----------------
__global__ __launch_bounds__(256) void cast_kernel(
    const float* __restrict__ x, const float* __restrict__ w,
    u16* __restrict__ xb, u16* __restrict__ wb)
{
  const int NX4 = M_*C_/4;     // 4194304
  const int NW4 = 2048*C_/4;   // 524288
  int tid = blockIdx.x*256 + threadIdx.x;
  int stride = gridDim.x*256;
  for (int i = tid; i < NX4; i += stride) {
    f32x4 v = ((const f32x4*)x)[i];
    ushort4 o;
    o.x = f2bf(v[0]); o.y = f2bf(v[1]); o.z = f2bf(v[2]); o.w = f2bf(v[3]);
    ((ushort4*)xb)[i] = o;
  }
  for (int i = tid; i < NW4; i += stride) {
    f32x4 v = ((const f32x4*)w)[i];
    ushort4 o;
    o.x = f2bf(v[0]); o.y = f2bf(v[1]); o.z = f2bf(v[2]); o.w = f2bf(v[3]);
    ((ushort4*)wb)[i] = o;
  }
}

// ---------------- kernel 1: qk GEMM + bias + elu+1 + ROPE -> q_rope,k_rope ----
// R9 core (verified 0-conflict). Output layout now HEAD-MAJOR: [b*16+h][n][64]
// (dense reads for attn A-stage and kvpart k-stream). Epilogue pairs RoPE
// results into u32 stores (even lanes store mf0-3, odd lanes mf4-7).
__global__ __launch_bounds__(512, 2) void gemm_kernel(
    const u16* __restrict__ xb, const u16* __restrict__ wb,
    const float* __restrict__ bqk,
    const float* __restrict__ ctab, const float* __restrict__ stab,
    u16* __restrict__ qrb, u16* __restrict__ krb)
{
  __shared__ __align__(16) unsigned char As[2][32768];  // [buf][256 rows][128B]
  __shared__ __align__(16) unsigned char Bs[2][32768];
  const int t = threadIdx.x;             // 0..511
  const int l = t & 63;
  const int w = t >> 6;                  // 0..7
  const int wm = w >> 2, wn = w & 3;     // 2M x 4N
  const int m0 = blockIdx.x * 256;
  const int n0 = blockIdx.y * 256;

  f32x4 acc[8][4];
  #pragma unroll
  for (int a = 0; a < 8; ++a)
    #pragma unroll
    for (int b = 0; b < 4; ++b) acc[a][b] = (f32x4){0.f,0.f,0.f,0.f};

  const int s_cole = ((t & 7) ^ ((t >> 3) & 7)) << 3;      // element offset 0..56
  const size_t a_base = (size_t)(m0 + (t >> 3)) * 1024 + s_cole;
  const size_t b_base = (size_t)(n0 + (t >> 3)) * 1024 + s_cole;

  #define GLA(buf, kt, i_)                                                     \
    __builtin_amdgcn_global_load_lds(                                          \
      (const __attribute__((address_space(1))) void*)(xb + a_base + (size_t)(i_)*65536 + (kt)*64), \
      (__attribute__((address_space(3))) void*)(&As[buf][((i_)*512 + w*64)*16]), 16, 0, 0)
  #define GLB(buf, kt, i_)                                                     \
    __builtin_amdgcn_global_load_lds(                                          \
      (const __attribute__((address_space(1))) void*)(wb + b_base + (size_t)(i_)*65536 + (kt)*64), \
      (__attribute__((address_space(3))) void*)(&Bs[buf][((i_)*512 + w*64)*16]), 16, 0, 0)

  GLA(0,0,0); GLA(0,0,1); GLA(0,0,2); GLA(0,0,3);
  GLB(0,0,0); GLB(0,0,1); GLB(0,0,2); GLB(0,0,3);
  asm volatile("s_waitcnt vmcnt(0)" ::: "memory");
  __builtin_amdgcn_s_barrier();

  for (int kt = 0; kt < NT_; ++kt) {
    const int cur = kt & 1;
    const int nx = cur ^ 1;
    const unsigned char* Ab = As[cur];
    const unsigned char* Bb = Bs[cur];
    s16x8 bfr[4][2];
    #pragma unroll
    for (int p = 0; p < 4; ++p) {
      s16x8 af[2][2];
      #pragma unroll
      for (int f = 0; f < 2; ++f) {
        const int r = wm*128 + (2*p + f)*16 + (l & 15);
        #pragma unroll
        for (int ks = 0; ks < 2; ++ks) {
          const int kbyte = ks*64 + ((l >> 4) << 4);
          af[f][ks] = *(const s16x8*)(Ab + r*128 + (kbyte ^ ((r & 7) << 4)));
        }
      }
      if (p == 0) {
        #pragma unroll
        for (int nf = 0; nf < 4; ++nf) {
          const int r = wn*64 + nf*16 + (l & 15);
          #pragma unroll
          for (int ks = 0; ks < 2; ++ks) {
            const int kbyte = ks*64 + ((l >> 4) << 4);
            bfr[nf][ks] = *(const s16x8*)(Bb + r*128 + (kbyte ^ ((r & 7) << 4)));
          }
        }
      }
      if (kt + 1 < NT_) {
        if (p == 0) { GLB(nx, kt+1, 0); GLB(nx, kt+1, 1); GLB(nx, kt+1, 2); GLB(nx, kt+1, 3); }
        if (p == 1) { GLA(nx, kt+1, 0); GLA(nx, kt+1, 2); }
        if (p == 2) { GLA(nx, kt+1, 1); GLA(nx, kt+1, 3); }
      }
      __builtin_amdgcn_s_barrier();
      __builtin_amdgcn_s_setprio(1);
      #pragma unroll
      for (int f = 0; f < 2; ++f)
        #pragma unroll
        for (int nf = 0; nf < 4; ++nf)
          #pragma unroll
          for (int ks = 0; ks < 2; ++ks)
            acc[2*p + f][nf] = __builtin_amdgcn_mfma_f32_16x16x32_bf16(
                af[f][ks], bfr[nf][ks], acc[2*p + f][nf], 0, 0, 0);
      __builtin_amdgcn_s_setprio(0);
      if (p == 1) {
        if (kt < NT_ - 1) asm volatile("s_waitcnt vmcnt(6)" ::: "memory");
        else              asm volatile("s_waitcnt vmcnt(0)" ::: "memory");
      }
      if (p == 3 && kt + 1 < NT_) {
        asm volatile("s_waitcnt vmcnt(2)" ::: "memory");
      }
      __builtin_amdgcn_s_barrier();
    }
  }
  #undef GLA
  #undef GLB

  // epilogue: bias + elu+1, rope; paired u32 stores, head-major output
  #pragma unroll
  for (int nf = 0; nf < 4; ++nf) {
    const int col = n0 + wn*64 + nf*16 + (l & 15);   // 0..2047 (parity == l&1)
    const float bias = bqk[col];
    const int cc = col & 1023;
    const float cn = ctab[cc >> 1];
    const float sn = stab[cc >> 1];
    u16* dst = (col < 1024) ? qrb : krb;
    const int hh = cc >> 6;
    const int dpair = (cc & 63) & ~1;
    #pragma unroll
    for (int mf = 0; mf < 8; ++mf) {
      #pragma unroll
      for (int j = 0; j < 4; ++j) {
        const int rowm = m0 + wm*128 + mf*16 + ((l >> 4) << 2) + j;
        float v = acc[mf][nf][j] + bias;
        v = (v > 0.f) ? (v + 1.f) : __expf(v);      // elu(v)+1
        const float vp = __shfl_xor(v, 1);          // partner column (elu'd)
        const float e = (l & 1) ? vp : v;           // even-col value
        const float o = (l & 1) ? v : vp;           // odd-col value
        const unsigned pack = (unsigned)f2bf(cn*e - sn*o)
                            | ((unsigned)f2bf(sn*e + cn*o) << 16);
        if ((mf >= 4) == (l & 1)) {
          const int bb = rowm >> 12, nn = rowm & 4095;
          *(unsigned*)(dst + ((size_t)(bb*16 + hh)*4096 + nn)*64 + dpair) = pack;
        }
      }
    }
  }
}

// ---------------- kernel 2: kv partials: 8d x 8e per thread, 32 n-slices ----------
// grid 2048 = bh(64) x ns(32); block 256 = nsub(4 waves) x dg(8) x eg(8)
// krb is head-major -> dense k-stream. partial (33.5MB) in d_out scratch.
__global__ __launch_bounds__(256, 4) void kvpart_kernel(
    const u16* __restrict__ krb, const u16* __restrict__ xb,
    float* __restrict__ partial, float* __restrict__ kmr)
{
  __shared__ float red[2][64][65];   // odd stride: conflict-free lane columns
  const int t = threadIdx.x;
  const int l = t & 63;
  const int nsub = t >> 6;
  const int dg = l >> 3, eg = l & 7;
  const int d0 = dg*8, e0 = eg*8;
  const int blk = blockIdx.x;
  const int bh = blk >> 5;
  const int ns = blk & 31;
  const int b = bh >> 4, h = bh & 15;

  float acc[8][8];
  #pragma unroll
  for (int i=0;i<8;++i)
    #pragma unroll
    for (int j=0;j<8;++j) acc[i][j]=0.f;
  float ksum[8];
  #pragma unroll
  for (int i=0;i<8;++i) ksum[i]=0.f;

  const size_t kbase = ((size_t)bh*4096 + ns*128 + nsub*32)*64 + d0;
  const size_t vbase = ((size_t)b*4096 + ns*128 + nsub*32)*1024 + h*64 + e0;
  #pragma unroll 4
  for (int it = 0; it < 32; ++it) {
    const s16x8 k8 = *(const s16x8*)(krb + kbase + (size_t)it*64);
    const s16x8 v8 = *(const s16x8*)(xb + vbase + (size_t)it*1024);
    float kf[8], vf[8];
    #pragma unroll
    for (int i=0;i<8;++i){ kf[i]=bf2f((u16)k8[i]); vf[i]=bf2f((u16)v8[i]); }
    #pragma unroll
    for (int i=0;i<8;++i){
      ksum[i]+=kf[i];
      #pragma unroll
      for (int j=0;j<8;++j) acc[i][j] += kf[i]*vf[j];
    }
  }

  if (nsub >= 2) {
    #pragma unroll
    for (int i=0;i<8;++i)
      #pragma unroll
      for (int j=0;j<8;++j) red[nsub-2][l][i*8+j] = acc[i][j];
  }
  __syncthreads();
  if (nsub < 2) {
    #pragma unroll
    for (int i=0;i<8;++i)
      #pragma unroll
      for (int j=0;j<8;++j) acc[i][j] += red[nsub][l][i*8+j];
  }
  __syncthreads();
  if (nsub == 1) {
    #pragma unroll
    for (int i=0;i<8;++i)
      #pragma unroll
      for (int j=0;j<8;++j) red[0][l][i*8+j] = acc[i][j];
  }
  __syncthreads();
  if (nsub == 0) {
    float* dst = partial + ((size_t)ns*64 + bh)*4096 + d0*64 + e0;
    #pragma unroll
    for (int i=0;i<8;++i) {
      f32x4 lo, hi;
      #pragma unroll
      for (int j=0;j<4;++j) { lo[j] = acc[i][j] + red[0][l][i*8+j];
                              hi[j] = acc[i][j+4] + red[0][l][i*8+j+4]; }
      *(f32x4*)(dst + i*64)     = lo;
      *(f32x4*)(dst + i*64 + 4) = hi;
    }
  }
  if (eg == 0) {
    #pragma unroll
    for (int i=0;i<8;++i)
      atomicAdd(kmr + bh*64 + d0 + i, ksum[i] * (1.f/4096.f));
  }
}

// ---------------- kernel 2b: sum 32 partial slices, *1/n, transpose -> kvbT bf16 ----
__global__ __launch_bounds__(256) void kvred_kernel(
    const float* __restrict__ partial, u16* __restrict__ kvbT)
{
  __shared__ float s[4096];
  const int bh = blockIdx.x;
  const int t = threadIdx.x;
  f32x4 a0={0,0,0,0}, a1={0,0,0,0}, a2={0,0,0,0}, a3={0,0,0,0};
  #pragma unroll
  for (int sl=0; sl<32; ++sl) {
    const f32x4* p = (const f32x4*)(partial + ((size_t)sl*64 + bh)*4096 + t*16);
    a0 += p[0]; a1 += p[1]; a2 += p[2]; a3 += p[3];
  }
  ((f32x4*)s)[t*4+0]=a0; ((f32x4*)s)[t*4+1]=a1;
  ((f32x4*)s)[t*4+2]=a2; ((f32x4*)s)[t*4+3]=a3;
  __syncthreads();
  const float inv_n = 1.f / 4096.f;
  s16x8 o0, o1;
  #pragma unroll
  for (int j=0;j<8;++j) {
    o0[j] = (short)f2bf(s[((t&3)*16 + j)*64 + (t>>2)] * inv_n);
    o1[j] = (short)f2bf(s[((t&3)*16 + 8 + j)*64 + (t>>2)] * inv_n);
  }
  *(s16x8*)(kvbT + (size_t)bh*4096 + t*16) = o0;
  *(s16x8*)(kvbT + (size_t)bh*4096 + t*16 + 8) = o1;
}

// ---------------- kernel 3: attn MFMA + fused z + z scale + fused pe conv ----------
// qrb is head-major -> dense A-stage. pe from xb (bf16, half traffic).
__global__ __launch_bounds__(256) void attn_kernel(
    const u16* __restrict__ qrb, const u16* __restrict__ kvbT,
    const float* __restrict__ kmr, const u16* __restrict__ xb,
    const float* __restrict__ lw, const float* __restrict__ lb,
    float* __restrict__ out)
{
  __shared__ __align__(16) unsigned char As[16384]; // 128 rows x 128B
  __shared__ __align__(16) unsigned char Bs[8192];  // 64 rows x 128B
  __shared__ float lws[192], lbs[64];
  __shared__ float kms[64];
  __shared__ float zs[128];
  const int t = threadIdx.x, l = t & 63, w = t >> 6;
  const int m0 = blockIdx.x * 128;
  const int h = blockIdx.y, b = blockIdx.z;
  const size_t qbase = ((size_t)(b*16 + h)*4096 + m0) * 64;   // head-major
  const u16* kvsrc = kvbT + ((size_t)(b*16 + h) << 12);

  #pragma unroll
  for (int i = 0; i < 4; ++i) {
    const int jc   = i*256 + t;
    const int row  = jc >> 3;                          // 0..127
    const int cole = (((jc & 7) << 4) ^ ((row & 7) << 4)) >> 1;
    const int ldsoff = (i*256 + w*64) * 16;
    __builtin_amdgcn_global_load_lds(
      (const __attribute__((address_space(1))) void*)(qrb + qbase + (size_t)row*64 + cole),
      (__attribute__((address_space(3))) void*)(As + ldsoff), 16, 0, 0);
  }
  #pragma unroll
  for (int i = 0; i < 2; ++i) {
    const int jc   = i*256 + t;
    const int row  = jc >> 3;                          // e: 0..63
    const int cole = (((jc & 7) << 4) ^ ((row & 7) << 4)) >> 1;
    const int ldsoff = (i*256 + w*64) * 16;
    __builtin_amdgcn_global_load_lds(
      (const __attribute__((address_space(1))) void*)(kvsrc + (size_t)row*64 + cole),
      (__attribute__((address_space(3))) void*)(Bs + ldsoff), 16, 0, 0);
  }
  if (t < 192) lws[t] = lw[h*192 + t];
  if (t >= 192)  lbs[t-192] = lb[h*64 + (t-192)];
  if (t < 64) kms[t] = kmr[(b*16 + h)*64 + t];
  __syncthreads();

  // fused z: row r = t>>1, d-half = t&1; q from swizzled As
  {
    const int r = t >> 1, half = t & 1;
    const int swz = (r & 7) << 4;
    float zp = 0.f;
    #pragma unroll
    for (int c = 0; c < 4; ++c) {
      const int kb = half*64 + c*16;
      const s16x8 qv = *(const s16x8*)(As + r*128 + (kb ^ swz));
      #pragma unroll
      for (int j = 0; j < 8; ++j) zp += bf2f((u16)qv[j]) * kms[half*32 + c*8 + j];
    }
    zp += __shfl_xor(zp, 1);
    if (!half) zs[r] = 1.f / (zp + 1e-6f);
  }

  f32x4 acc[2][4];
  #pragma unroll
  for (int a = 0; a < 2; ++a)
    #pragma unroll
    for (int c = 0; c < 4; ++c) acc[a][c] = (f32x4){0.f,0.f,0.f,0.f};

  #pragma unroll
  for (int ks = 0; ks < 2; ++ks) {
    const int kbyte = ks*64 + ((l >> 4) << 4);
    s16x8 af[2], bf[4];
    #pragma unroll
    for (int mi = 0; mi < 2; ++mi) {
      const int r = w*32 + mi*16 + (l & 15);
      af[mi] = *(const s16x8*)(As + r*128 + (kbyte ^ ((r & 7) << 4)));
    }
    #pragma unroll
    for (int ni = 0; ni < 4; ++ni) {
      const int r = ni*16 + (l & 15);
      bf[ni] = *(const s16x8*)(Bs + r*128 + (kbyte ^ ((r & 7) << 4)));
    }
    #pragma unroll
    for (int mi = 0; mi < 2; ++mi)
      #pragma unroll
      for (int ni = 0; ni < 4; ++ni)
        acc[mi][ni] = __builtin_amdgcn_mfma_f32_16x16x32_bf16(af[mi], bf[ni], acc[mi][ni], 0, 0, 0);
  }
  __syncthreads();   // zs ready for epilogue

  // epilogue: out = acc * z[row] + pe(xb)
  #pragma unroll
  for (int mi = 0; mi < 2; ++mi) {
    #pragma unroll
    for (int j = 0; j < 4; ++j) {
      const int rowm = m0 + w*32 + mi*16 + ((l >> 4) << 2) + j;
      const float zr = zs[rowm - m0];
      const size_t rbase = ((size_t)b*4096 + rowm)*1024;
      #pragma unroll
      for (int ni = 0; ni < 4; ++ni) {
        const int cl = ni*16 + (l & 15);       // in-head channel 0..63
        const int c = h*64 + cl;
        float pe = lbs[cl] + bf2f(xb[rbase + c])*lws[cl*3+1];
        if (rowm > 0)    pe += bf2f(xb[rbase - 1024 + c])*lws[cl*3];
        if (rowm < 4095) pe += bf2f(xb[rbase + 1024 + c])*lws[cl*3+2];
        out[rbase + c] = acc[mi][ni][j]*zr + pe;
      }
    }
  }
}

extern "C" void kernel_launch(void* const* d_in, const int* in_sizes, int n_in,
                              void* d_out, int out_size, void* d_ws, size_t ws_size,
                              hipStream_t stream) {
  const float* x   = (const float*)d_in[0];
  const float* Wqk = (const float*)d_in[1];
  const float* bqk = (const float*)d_in[2];
  const float* lw  = (const float*)d_in[3];
  const float* lb  = (const float*)d_in[4];
  float* out = (float*)d_out;

  char* ws = (char*)d_ws;
  u16* xb    = (u16*)(ws);                       // 33.55 MB  x bf16
  u16* qrb   = (u16*)(ws + 33554432ull);         // 33.55 MB  q_rope bf16 (head-major)
  u16* krb   = (u16*)(ws + 67108864ull);         // 33.55 MB  k_rope bf16 (head-major)
  u16* wb    = (u16*)(ws + 100663296ull);        //  4.19 MB  W bf16
  float* kmr = (float*)(ws + 104857600ull);      // 16 KB     fp32
  float* ctab= (float*)(ws + 104874368ull);      //  2 KB
  float* stab= (float*)(ws + 104876416ull);      //  2 KB
  u16* kvbT  = (u16*)(ws + 104878464ull);        // 0.5 MB    kv^T bf16
  // kv partials (33.5 MB fp32) live in d_out scratch; attn overwrites all of out later.
  float* partial = out;

  hipMemsetAsync(kmr, 0, 16384ull, stream);      // atomic target only
  hipLaunchKernelGGL(trig_kernel, dim3(1), dim3(512), 0, stream, ctab, stab);
  hipLaunchKernelGGL(cast_kernel, dim3(2048), dim3(256), 0, stream, x, Wqk, xb, wb);
  hipLaunchKernelGGL(gemm_kernel, dim3(64, 8), dim3(512), 0, stream, xb, wb, bqk, ctab, stab, qrb, krb);
  hipLaunchKernelGGL(kvpart_kernel, dim3(2048), dim3(256), 0, stream, krb, xb, partial, kmr);
  hipLaunchKernelGGL(kvred_kernel, dim3(64), dim3(256), 0, stream, partial, kvbT);
  hipLaunchKernelGGL(attn_kernel, dim3(32, 16, 4), dim3(256), 0, stream, qrb, kvbT, kmr, xb, lw, lb, out);
}

// Round 12
// 251.945 us; speedup vs baseline: 1.2786x; 1.2786x over previous
//
#include <hip/hip_runtime.h>
#include <hip/hip_bf16.h>
#include <math.h>

typedef unsigned short u16;
typedef __attribute__((ext_vector_type(8))) short s16x8;
typedef __attribute__((ext_vector_type(4))) float f32x4;

#define B_ 4
#define N_ 4096
#define C_ 1024
#define M_ (B_*N_)
#define NT_ 16   // K / 64

__device__ __forceinline__ u16 f2bf(float f) {
  unsigned u = __builtin_bit_cast(unsigned, f);
  u = u + 0x7fffu + ((u >> 16) & 1u);
  return (u16)(u >> 16);
}
__device__ __forceinline__ float bf2f(u16 h) {
  unsigned u = ((unsigned)h) << 16;
  return __builtin_bit_cast(float, u);
}

// ---------------- kernel T: one-time rope trig table (512 pairs) ----------------
__global__ void trig_kernel(float* __restrict__ ctab, float* __restrict__ stab) {
  const int i = threadIdx.x;   // 0..511
  const float theta = powf(10000.f, -(float)i * (1.f/512.f));
  ctab[i] = cosf(theta);
  stab[i] = sinf(theta);
}

// ---------------- kernel 0: fp32 -> bf16 precast of x and W ----------------
__global__ __launch_bounds__(256) void cast_kernel(
    const float* __restrict__ x, const float* __restrict__ w,
    u16* __restrict__ xb, u16* __restrict__ wb)
{
  const int NX4 = M_*C_/4;     // 4194304
  const int NW4 = 2048*C_/4;   // 524288
  int tid = blockIdx.x*256 + threadIdx.x;
  int stride = gridDim.x*256;
  for (int i = tid; i < NX4; i += stride) {
    f32x4 v = ((const f32x4*)x)[i];
    ushort4 o;
    o.x = f2bf(v[0]); o.y = f2bf(v[1]); o.z = f2bf(v[2]); o.w = f2bf(v[3]);
    ((ushort4*)xb)[i] = o;
  }
  for (int i = tid; i < NW4; i += stride) {
    f32x4 v = ((const f32x4*)w)[i];
    ushort4 o;
    o.x = f2bf(v[0]); o.y = f2bf(v[1]); o.z = f2bf(v[2]); o.w = f2bf(v[3]);
    ((ushort4*)wb)[i] = o;
  }
}

// ---------------- kernel 1: qk GEMM + bias + elu+1 + ROPE -> q_rope,k_rope ----
// R9 core (verified 0-conflict). Output HEAD-MAJOR: [b*16+h][n][64].
__global__ __launch_bounds__(512, 2) void gemm_kernel(
    const u16* __restrict__ xb, const u16* __restrict__ wb,
    const float* __restrict__ bqk,
    const float* __restrict__ ctab, const float* __restrict__ stab,
    u16* __restrict__ qrb, u16* __restrict__ krb)
{
  __shared__ __align__(16) unsigned char As[2][32768];  // [buf][256 rows][128B]
  __shared__ __align__(16) unsigned char Bs[2][32768];
  const int t = threadIdx.x;             // 0..511
  const int l = t & 63;
  const int w = t >> 6;                  // 0..7
  const int wm = w >> 2, wn = w & 3;     // 2M x 4N
  const int m0 = blockIdx.x * 256;
  const int n0 = blockIdx.y * 256;

  f32x4 acc[8][4];
  #pragma unroll
  for (int a = 0; a < 8; ++a)
    #pragma unroll
    for (int b = 0; b < 4; ++b) acc[a][b] = (f32x4){0.f,0.f,0.f,0.f};

  const int s_cole = ((t & 7) ^ ((t >> 3) & 7)) << 3;      // element offset 0..56
  const size_t a_base = (size_t)(m0 + (t >> 3)) * 1024 + s_cole;
  const size_t b_base = (size_t)(n0 + (t >> 3)) * 1024 + s_cole;

  #define GLA(buf, kt, i_)                                                     \
    __builtin_amdgcn_global_load_lds(                                          \
      (const __attribute__((address_space(1))) void*)(xb + a_base + (size_t)(i_)*65536 + (kt)*64), \
      (__attribute__((address_space(3))) void*)(&As[buf][((i_)*512 + w*64)*16]), 16, 0, 0)
  #define GLB(buf, kt, i_)                                                     \
    __builtin_amdgcn_global_load_lds(                                          \
      (const __attribute__((address_space(1))) void*)(wb + b_base + (size_t)(i_)*65536 + (kt)*64), \
      (__attribute__((address_space(3))) void*)(&Bs[buf][((i_)*512 + w*64)*16]), 16, 0, 0)

  GLA(0,0,0); GLA(0,0,1); GLA(0,0,2); GLA(0,0,3);
  GLB(0,0,0); GLB(0,0,1); GLB(0,0,2); GLB(0,0,3);
  asm volatile("s_waitcnt vmcnt(0)" ::: "memory");
  __builtin_amdgcn_s_barrier();

  for (int kt = 0; kt < NT_; ++kt) {
    const int cur = kt & 1;
    const int nx = cur ^ 1;
    const unsigned char* Ab = As[cur];
    const unsigned char* Bb = Bs[cur];
    s16x8 bfr[4][2];
    #pragma unroll
    for (int p = 0; p < 4; ++p) {
      s16x8 af[2][2];
      #pragma unroll
      for (int f = 0; f < 2; ++f) {
        const int r = wm*128 + (2*p + f)*16 + (l & 15);
        #pragma unroll
        for (int ks = 0; ks < 2; ++ks) {
          const int kbyte = ks*64 + ((l >> 4) << 4);
          af[f][ks] = *(const s16x8*)(Ab + r*128 + (kbyte ^ ((r & 7) << 4)));
        }
      }
      if (p == 0) {
        #pragma unroll
        for (int nf = 0; nf < 4; ++nf) {
          const int r = wn*64 + nf*16 + (l & 15);
          #pragma unroll
          for (int ks = 0; ks < 2; ++ks) {
            const int kbyte = ks*64 + ((l >> 4) << 4);
            bfr[nf][ks] = *(const s16x8*)(Bb + r*128 + (kbyte ^ ((r & 7) << 4)));
          }
        }
      }
      if (kt + 1 < NT_) {
        if (p == 0) { GLB(nx, kt+1, 0); GLB(nx, kt+1, 1); GLB(nx, kt+1, 2); GLB(nx, kt+1, 3); }
        if (p == 1) { GLA(nx, kt+1, 0); GLA(nx, kt+1, 2); }
        if (p == 2) { GLA(nx, kt+1, 1); GLA(nx, kt+1, 3); }
      }
      __builtin_amdgcn_s_barrier();
      __builtin_amdgcn_s_setprio(1);
      #pragma unroll
      for (int f = 0; f < 2; ++f)
        #pragma unroll
        for (int nf = 0; nf < 4; ++nf)
          #pragma unroll
          for (int ks = 0; ks < 2; ++ks)
            acc[2*p + f][nf] = __builtin_amdgcn_mfma_f32_16x16x32_bf16(
                af[f][ks], bfr[nf][ks], acc[2*p + f][nf], 0, 0, 0);
      __builtin_amdgcn_s_setprio(0);
      if (p == 1) {
        if (kt < NT_ - 1) asm volatile("s_waitcnt vmcnt(6)" ::: "memory");
        else              asm volatile("s_waitcnt vmcnt(0)" ::: "memory");
      }
      if (p == 3 && kt + 1 < NT_) {
        asm volatile("s_waitcnt vmcnt(2)" ::: "memory");
      }
      __builtin_amdgcn_s_barrier();
    }
  }
  #undef GLA
  #undef GLB

  // epilogue: bias + elu+1, rope; paired u32 stores, head-major output
  #pragma unroll
  for (int nf = 0; nf < 4; ++nf) {
    const int col = n0 + wn*64 + nf*16 + (l & 15);   // 0..2047 (parity == l&1)
    const float bias = bqk[col];
    const int cc = col & 1023;
    const float cn = ctab[cc >> 1];
    const float sn = stab[cc >> 1];
    u16* dst = (col < 1024) ? qrb : krb;
    const int hh = cc >> 6;
    const int dpair = (cc & 63) & ~1;
    #pragma unroll
    for (int mf = 0; mf < 8; ++mf) {
      #pragma unroll
      for (int j = 0; j < 4; ++j) {
        const int rowm = m0 + wm*128 + mf*16 + ((l >> 4) << 2) + j;
        float v = acc[mf][nf][j] + bias;
        v = (v > 0.f) ? (v + 1.f) : __expf(v);      // elu(v)+1
        const float vp = __shfl_xor(v, 1);          // partner column (elu'd)
        const float e = (l & 1) ? vp : v;           // even-col value
        const float o = (l & 1) ? v : vp;           // odd-col value
        const unsigned pack = (unsigned)f2bf(cn*e - sn*o)
                            | ((unsigned)f2bf(sn*e + cn*o) << 16);
        if ((mf >= 4) == (l & 1)) {
          const int bb = rowm >> 12, nn = rowm & 4095;
          *(unsigned*)(dst + ((size_t)(bb*16 + hh)*4096 + nn)*64 + dpair) = pack;
        }
      }
    }
  }
}

// ---------------- kernel 2: kv partials: 8d x 8e per thread, 16 n-slices ----------
// EXACT R10 shape (grid 1024 = bh x 16ns, 64-iter loop, unroll 2) -- only kbase
// adapted to head-major krb. R11's 2048/32-iter/unroll4 variant flipped regalloc
// (VGPR_Count=64 < live state -> acc off-file, 2.5x slower).
__global__ __launch_bounds__(256, 4) void kvpart_kernel(
    const u16* __restrict__ krb, const u16* __restrict__ xb,
    float* __restrict__ partial, float* __restrict__ kmr)
{
  __shared__ float red[2][64][65];   // odd stride: conflict-free lane columns
  const int t = threadIdx.x;
  const int l = t & 63;
  const int nsub = t >> 6;
  const int dg = l >> 3, eg = l & 7;
  const int d0 = dg*8, e0 = eg*8;
  const int blk = blockIdx.x;
  const int bh = blk >> 4;
  const int ns = blk & 15;
  const int b = bh >> 4, h = bh & 15;

  float acc[8][8];
  #pragma unroll
  for (int i=0;i<8;++i)
    #pragma unroll
    for (int j=0;j<8;++j) acc[i][j]=0.f;
  float ksum[8];
  #pragma unroll
  for (int i=0;i<8;++i) ksum[i]=0.f;

  const size_t kbase = ((size_t)bh*4096 + ns*256 + nsub*64)*64 + d0;
  const size_t vbase = ((size_t)b*4096 + ns*256 + nsub*64)*1024 + h*64 + e0;
  #pragma unroll 2
  for (int it = 0; it < 64; ++it) {
    const s16x8 k8 = *(const s16x8*)(krb + kbase + (size_t)it*64);
    const s16x8 v8 = *(const s16x8*)(xb + vbase + (size_t)it*1024);
    float kf[8], vf[8];
    #pragma unroll
    for (int i=0;i<8;++i){ kf[i]=bf2f((u16)k8[i]); vf[i]=bf2f((u16)v8[i]); }
    #pragma unroll
    for (int i=0;i<8;++i){
      ksum[i]+=kf[i];
      #pragma unroll
      for (int j=0;j<8;++j) acc[i][j] += kf[i]*vf[j];
    }
  }

  if (nsub >= 2) {
    #pragma unroll
    for (int i=0;i<8;++i)
      #pragma unroll
      for (int j=0;j<8;++j) red[nsub-2][l][i*8+j] = acc[i][j];
  }
  __syncthreads();
  if (nsub < 2) {
    #pragma unroll
    for (int i=0;i<8;++i)
      #pragma unroll
      for (int j=0;j<8;++j) acc[i][j] += red[nsub][l][i*8+j];
  }
  __syncthreads();
  if (nsub == 1) {
    #pragma unroll
    for (int i=0;i<8;++i)
      #pragma unroll
      for (int j=0;j<8;++j) red[0][l][i*8+j] = acc[i][j];
  }
  __syncthreads();
  if (nsub == 0) {
    float* dst = partial + ((size_t)ns*64 + bh)*4096 + d0*64 + e0;
    #pragma unroll
    for (int i=0;i<8;++i) {
      f32x4 lo, hi;
      #pragma unroll
      for (int j=0;j<4;++j) { lo[j] = acc[i][j] + red[0][l][i*8+j];
                              hi[j] = acc[i][j+4] + red[0][l][i*8+j+4]; }
      *(f32x4*)(dst + i*64)     = lo;
      *(f32x4*)(dst + i*64 + 4) = hi;
    }
  }
  if (eg == 0) {
    #pragma unroll
    for (int i=0;i<8;++i)
      atomicAdd(kmr + bh*64 + d0 + i, ksum[i] * (1.f/4096.f));
  }
}

// ---------------- kernel 2b: sum 16 partial slices, *1/n, transpose -> kvbT bf16 ----
__global__ __launch_bounds__(256) void kvred_kernel(
    const float* __restrict__ partial, u16* __restrict__ kvbT)
{
  __shared__ float s[4096];
  const int bh = blockIdx.x;
  const int t = threadIdx.x;
  f32x4 a0={0,0,0,0}, a1={0,0,0,0}, a2={0,0,0,0}, a3={0,0,0,0};
  #pragma unroll
  for (int sl=0; sl<16; ++sl) {
    const f32x4* p = (const f32x4*)(partial + ((size_t)sl*64 + bh)*4096 + t*16);
    a0 += p[0]; a1 += p[1]; a2 += p[2]; a3 += p[3];
  }
  ((f32x4*)s)[t*4+0]=a0; ((f32x4*)s)[t*4+1]=a1;
  ((f32x4*)s)[t*4+2]=a2; ((f32x4*)s)[t*4+3]=a3;
  __syncthreads();
  const float inv_n = 1.f / 4096.f;
  s16x8 o0, o1;
  #pragma unroll
  for (int j=0;j<8;++j) {
    o0[j] = (short)f2bf(s[((t&3)*16 + j)*64 + (t>>2)] * inv_n);
    o1[j] = (short)f2bf(s[((t&3)*16 + 8 + j)*64 + (t>>2)] * inv_n);
  }
  *(s16x8*)(kvbT + (size_t)bh*4096 + t*16) = o0;
  *(s16x8*)(kvbT + (size_t)bh*4096 + t*16 + 8) = o1;
}

// ---------------- kernel 3: attn MFMA + fused z + z scale + fused pe conv ----------
// qrb is head-major -> dense A-stage. pe from xb (bf16, half traffic).
__global__ __launch_bounds__(256) void attn_kernel(
    const u16* __restrict__ qrb, const u16* __restrict__ kvbT,
    const float* __restrict__ kmr, const u16* __restrict__ xb,
    const float* __restrict__ lw, const float* __restrict__ lb,
    float* __restrict__ out)
{
  __shared__ __align__(16) unsigned char As[16384]; // 128 rows x 128B
  __shared__ __align__(16) unsigned char Bs[8192];  // 64 rows x 128B
  __shared__ float lws[192], lbs[64];
  __shared__ float kms[64];
  __shared__ float zs[128];
  const int t = threadIdx.x, l = t & 63, w = t >> 6;
  const int m0 = blockIdx.x * 128;
  const int h = blockIdx.y, b = blockIdx.z;
  const size_t qbase = ((size_t)(b*16 + h)*4096 + m0) * 64;   // head-major
  const u16* kvsrc = kvbT + ((size_t)(b*16 + h) << 12);

  #pragma unroll
  for (int i = 0; i < 4; ++i) {
    const int jc   = i*256 + t;
    const int row  = jc >> 3;                          // 0..127
    const int cole = (((jc & 7) << 4) ^ ((row & 7) << 4)) >> 1;
    const int ldsoff = (i*256 + w*64) * 16;
    __builtin_amdgcn_global_load_lds(
      (const __attribute__((address_space(1))) void*)(qrb + qbase + (size_t)row*64 + cole),
      (__attribute__((address_space(3))) void*)(As + ldsoff), 16, 0, 0);
  }
  #pragma unroll
  for (int i = 0; i < 2; ++i) {
    const int jc   = i*256 + t;
    const int row  = jc >> 3;                          // e: 0..63
    const int cole = (((jc & 7) << 4) ^ ((row & 7) << 4)) >> 1;
    const int ldsoff = (i*256 + w*64) * 16;
    __builtin_amdgcn_global_load_lds(
      (const __attribute__((address_space(1))) void*)(kvsrc + (size_t)row*64 + cole),
      (__attribute__((address_space(3))) void*)(Bs + ldsoff), 16, 0, 0);
  }
  if (t < 192) lws[t] = lw[h*192 + t];
  if (t >= 192)  lbs[t-192] = lb[h*64 + (t-192)];
  if (t < 64) kms[t] = kmr[(b*16 + h)*64 + t];
  __syncthreads();

  // fused z: row r = t>>1, d-half = t&1; q from swizzled As
  {
    const int r = t >> 1, half = t & 1;
    const int swz = (r & 7) << 4;
    float zp = 0.f;
    #pragma unroll
    for (int c = 0; c < 4; ++c) {
      const int kb = half*64 + c*16;
      const s16x8 qv = *(const s16x8*)(As + r*128 + (kb ^ swz));
      #pragma unroll
      for (int j = 0; j < 8; ++j) zp += bf2f((u16)qv[j]) * kms[half*32 + c*8 + j];
    }
    zp += __shfl_xor(zp, 1);
    if (!half) zs[r] = 1.f / (zp + 1e-6f);
  }

  f32x4 acc[2][4];
  #pragma unroll
  for (int a = 0; a < 2; ++a)
    #pragma unroll
    for (int c = 0; c < 4; ++c) acc[a][c] = (f32x4){0.f,0.f,0.f,0.f};

  #pragma unroll
  for (int ks = 0; ks < 2; ++ks) {
    const int kbyte = ks*64 + ((l >> 4) << 4);
    s16x8 af[2], bf[4];
    #pragma unroll
    for (int mi = 0; mi < 2; ++mi) {
      const int r = w*32 + mi*16 + (l & 15);
      af[mi] = *(const s16x8*)(As + r*128 + (kbyte ^ ((r & 7) << 4)));
    }
    #pragma unroll
    for (int ni = 0; ni < 4; ++ni) {
      const int r = ni*16 + (l & 15);
      bf[ni] = *(const s16x8*)(Bs + r*128 + (kbyte ^ ((r & 7) << 4)));
    }
    #pragma unroll
    for (int mi = 0; mi < 2; ++mi)
      #pragma unroll
      for (int ni = 0; ni < 4; ++ni)
        acc[mi][ni] = __builtin_amdgcn_mfma_f32_16x16x32_bf16(af[mi], bf[ni], acc[mi][ni], 0, 0, 0);
  }
  __syncthreads();   // zs ready for epilogue

  // epilogue: out = acc * z[row] + pe(xb)
  #pragma unroll
  for (int mi = 0; mi < 2; ++mi) {
    #pragma unroll
    for (int j = 0; j < 4; ++j) {
      const int rowm = m0 + w*32 + mi*16 + ((l >> 4) << 2) + j;
      const float zr = zs[rowm - m0];
      const size_t rbase = ((size_t)b*4096 + rowm)*1024;
      #pragma unroll
      for (int ni = 0; ni < 4; ++ni) {
        const int cl = ni*16 + (l & 15);       // in-head channel 0..63
        const int c = h*64 + cl;
        float pe = lbs[cl] + bf2f(xb[rbase + c])*lws[cl*3+1];
        if (rowm > 0)    pe += bf2f(xb[rbase - 1024 + c])*lws[cl*3];
        if (rowm < 4095) pe += bf2f(xb[rbase + 1024 + c])*lws[cl*3+2];
        out[rbase + c] = acc[mi][ni][j]*zr + pe;
      }
    }
  }
}

extern "C" void kernel_launch(void* const* d_in, const int* in_sizes, int n_in,
                              void* d_out, int out_size, void* d_ws, size_t ws_size,
                              hipStream_t stream) {
  const float* x   = (const float*)d_in[0];
  const float* Wqk = (const float*)d_in[1];
  const float* bqk = (const float*)d_in[2];
  const float* lw  = (const float*)d_in[3];
  const float* lb  = (const float*)d_in[4];
  float* out = (float*)d_out;

  char* ws = (char*)d_ws;
  u16* xb    = (u16*)(ws);                       // 33.55 MB  x bf16
  u16* qrb   = (u16*)(ws + 33554432ull);         // 33.55 MB  q_rope bf16 (head-major)
  u16* krb   = (u16*)(ws + 67108864ull);         // 33.55 MB  k_rope bf16 (head-major)
  u16* wb    = (u16*)(ws + 100663296ull);        //  4.19 MB  W bf16
  float* kmr = (float*)(ws + 104857600ull);      // 16 KB     fp32
  float* ctab= (float*)(ws + 104874368ull);      //  2 KB
  float* stab= (float*)(ws + 104876416ull);      //  2 KB
  u16* kvbT  = (u16*)(ws + 104878464ull);        // 0.5 MB    kv^T bf16
  // kv partials (16.7 MB fp32) live in d_out scratch; attn overwrites all of out later.
  float* partial = out;

  hipMemsetAsync(kmr, 0, 16384ull, stream);      // atomic target only
  hipLaunchKernelGGL(trig_kernel, dim3(1), dim3(512), 0, stream, ctab, stab);
  hipLaunchKernelGGL(cast_kernel, dim3(2048), dim3(256), 0, stream, x, Wqk, xb, wb);
  hipLaunchKernelGGL(gemm_kernel, dim3(64, 8), dim3(512), 0, stream, xb, wb, bqk, ctab, stab, qrb, krb);
  hipLaunchKernelGGL(kvpart_kernel, dim3(1024), dim3(256), 0, stream, krb, xb, partial, kmr);
  hipLaunchKernelGGL(kvred_kernel, dim3(64), dim3(256), 0, stream, partial, kvbT);
  hipLaunchKernelGGL(attn_kernel, dim3(32, 16, 4), dim3(256), 0, stream, qrb, kvbT, kmr, xb, lw, lb, out);
}

// Round 13
// 240.663 us; speedup vs baseline: 1.3385x; 1.0469x over previous
//
#include <hip/hip_runtime.h>
#include <hip/hip_bf16.h>
#include <math.h>

typedef unsigned short u16;
typedef __attribute__((ext_vector_type(8))) short s16x8;
typedef __attribute__((ext_vector_type(4))) float f32x4;

#define B_ 4
#define N_ 4096
#define C_ 1024
#define M_ (B_*N_)
#define NT_ 16   // K / 64

__device__ __forceinline__ u16 f2bf(float f) {
  unsigned u = __builtin_bit_cast(unsigned, f);
  u = u + 0x7fffu + ((u >> 16) & 1u);
  return (u16)(u >> 16);
}
__device__ __forceinline__ float bf2f(u16 h) {
  unsigned u = ((unsigned)h) << 16;
  return __builtin_bit_cast(float, u);
}

// ---------------- kernel T: one-time rope trig table (512 pairs) ----------------
__global__ void trig_kernel(float* __restrict__ ctab, float* __restrict__ stab) {
  const int i = threadIdx.x;   // 0..511
  const float theta = powf(10000.f, -(float)i * (1.f/512.f));
  ctab[i] = cosf(theta);
  stab[i] = sinf(theta);
}

// ---------------- kernel 0: fp32 -> bf16 precast of x and W ----------------
__global__ __launch_bounds__(256) void cast_kernel(
    const float* __restrict__ x, const float* __restrict__ w,
    u16* __restrict__ xb, u16* __restrict__ wb)
{
  const int NX4 = M_*C_/4;     // 4194304
  const int NW4 = 2048*C_/4;   // 524288
  int tid = blockIdx.x*256 + threadIdx.x;
  int stride = gridDim.x*256;
  for (int i = tid; i < NX4; i += stride) {
    f32x4 v = ((const f32x4*)x)[i];
    ushort4 o;
    o.x = f2bf(v[0]); o.y = f2bf(v[1]); o.z = f2bf(v[2]); o.w = f2bf(v[3]);
    ((ushort4*)xb)[i] = o;
  }
  for (int i = tid; i < NW4; i += stride) {
    f32x4 v = ((const f32x4*)w)[i];
    ushort4 o;
    o.x = f2bf(v[0]); o.y = f2bf(v[1]); o.z = f2bf(v[2]); o.w = f2bf(v[3]);
    ((ushort4*)wb)[i] = o;
  }
}

// ---------------- kernel 1: qk GEMM + bias + elu+1 + ROPE -> q_rope,k_rope ----
// 256x256 tile, BK=64, 8 waves (2M x 4N), dbuf LDS. Use-ordered split staging:
// B(kt+1)@p0, A-half-early@p1, A-half-late@p2; COUNTED waits vmcnt(6)@p1-end,
// vmcnt(2)@p3-end. Row-major outputs (R9-exact, verified 99-101 us).
__global__ __launch_bounds__(512, 2) void gemm_kernel(
    const u16* __restrict__ xb, const u16* __restrict__ wb,
    const float* __restrict__ bqk,
    const float* __restrict__ ctab, const float* __restrict__ stab,
    u16* __restrict__ qrb, u16* __restrict__ krb)
{
  __shared__ __align__(16) unsigned char As[2][32768];  // [buf][256 rows][128B]
  __shared__ __align__(16) unsigned char Bs[2][32768];
  const int t = threadIdx.x;             // 0..511
  const int l = t & 63;
  const int w = t >> 6;                  // 0..7
  const int wm = w >> 2, wn = w & 3;     // 2M x 4N
  const int m0 = blockIdx.x * 256;
  const int n0 = blockIdx.y * 256;

  f32x4 acc[8][4];
  #pragma unroll
  for (int a = 0; a < 8; ++a)
    #pragma unroll
    for (int b = 0; b < 4; ++b) acc[a][b] = (f32x4){0.f,0.f,0.f,0.f};

  const int s_cole = ((t & 7) ^ ((t >> 3) & 7)) << 3;      // element offset 0..56
  const size_t a_base = (size_t)(m0 + (t >> 3)) * 1024 + s_cole;
  const size_t b_base = (size_t)(n0 + (t >> 3)) * 1024 + s_cole;

  #define GLA(buf, kt, i_)                                                     \
    __builtin_amdgcn_global_load_lds(                                          \
      (const __attribute__((address_space(1))) void*)(xb + a_base + (size_t)(i_)*65536 + (kt)*64), \
      (__attribute__((address_space(3))) void*)(&As[buf][((i_)*512 + w*64)*16]), 16, 0, 0)
  #define GLB(buf, kt, i_)                                                     \
    __builtin_amdgcn_global_load_lds(                                          \
      (const __attribute__((address_space(1))) void*)(wb + b_base + (size_t)(i_)*65536 + (kt)*64), \
      (__attribute__((address_space(3))) void*)(&Bs[buf][((i_)*512 + w*64)*16]), 16, 0, 0)

  GLA(0,0,0); GLA(0,0,1); GLA(0,0,2); GLA(0,0,3);
  GLB(0,0,0); GLB(0,0,1); GLB(0,0,2); GLB(0,0,3);
  asm volatile("s_waitcnt vmcnt(0)" ::: "memory");
  __builtin_amdgcn_s_barrier();

  for (int kt = 0; kt < NT_; ++kt) {
    const int cur = kt & 1;
    const int nx = cur ^ 1;
    const unsigned char* Ab = As[cur];
    const unsigned char* Bb = Bs[cur];
    s16x8 bfr[4][2];
    #pragma unroll
    for (int p = 0; p < 4; ++p) {
      s16x8 af[2][2];
      #pragma unroll
      for (int f = 0; f < 2; ++f) {
        const int r = wm*128 + (2*p + f)*16 + (l & 15);
        #pragma unroll
        for (int ks = 0; ks < 2; ++ks) {
          const int kbyte = ks*64 + ((l >> 4) << 4);
          af[f][ks] = *(const s16x8*)(Ab + r*128 + (kbyte ^ ((r & 7) << 4)));
        }
      }
      if (p == 0) {
        #pragma unroll
        for (int nf = 0; nf < 4; ++nf) {
          const int r = wn*64 + nf*16 + (l & 15);
          #pragma unroll
          for (int ks = 0; ks < 2; ++ks) {
            const int kbyte = ks*64 + ((l >> 4) << 4);
            bfr[nf][ks] = *(const s16x8*)(Bb + r*128 + (kbyte ^ ((r & 7) << 4)));
          }
        }
      }
      if (kt + 1 < NT_) {
        if (p == 0) { GLB(nx, kt+1, 0); GLB(nx, kt+1, 1); GLB(nx, kt+1, 2); GLB(nx, kt+1, 3); }
        if (p == 1) { GLA(nx, kt+1, 0); GLA(nx, kt+1, 2); }
        if (p == 2) { GLA(nx, kt+1, 1); GLA(nx, kt+1, 3); }
      }
      __builtin_amdgcn_s_barrier();
      __builtin_amdgcn_s_setprio(1);
      #pragma unroll
      for (int f = 0; f < 2; ++f)
        #pragma unroll
        for (int nf = 0; nf < 4; ++nf)
          #pragma unroll
          for (int ks = 0; ks < 2; ++ks)
            acc[2*p + f][nf] = __builtin_amdgcn_mfma_f32_16x16x32_bf16(
                af[f][ks], bfr[nf][ks], acc[2*p + f][nf], 0, 0, 0);
      __builtin_amdgcn_s_setprio(0);
      if (p == 1) {
        if (kt < NT_ - 1) asm volatile("s_waitcnt vmcnt(6)" ::: "memory");
        else              asm volatile("s_waitcnt vmcnt(0)" ::: "memory");
      }
      if (p == 3 && kt + 1 < NT_) {
        asm volatile("s_waitcnt vmcnt(2)" ::: "memory");
      }
      __builtin_amdgcn_s_barrier();
    }
  }
  #undef GLA
  #undef GLB

  // epilogue: bias + elu+1, rope via shfl_xor(1), split q/k (R9-exact, row-major)
  #pragma unroll
  for (int nf = 0; nf < 4; ++nf) {
    const int col = n0 + wn*64 + nf*16 + (l & 15);   // 0..2047
    const float bias = bqk[col];
    const int cc = col & 1023;
    const float cn = ctab[cc >> 1];
    const float sn = stab[cc >> 1];
    u16* dst = (col < 1024) ? qrb : krb;
    #pragma unroll
    for (int mf = 0; mf < 8; ++mf) {
      #pragma unroll
      for (int j = 0; j < 4; ++j) {
        const int rowm = m0 + wm*128 + mf*16 + ((l >> 4) << 2) + j;
        float v = acc[mf][nf][j] + bias;
        v = (v > 0.f) ? (v + 1.f) : __expf(v);      // elu(v)+1
        const float vp = __shfl_xor(v, 1);          // partner column (elu'd)
        const float vr = (col & 1) ? (sn*vp + cn*v) : (cn*v - sn*vp);
        dst[(size_t)rowm*1024 + cc] = f2bf(vr);
      }
    }
  }
}

// ---------------- kernel 2: kv partials: 8d x 8e per thread, 16 n-slices ----------
// R9-exact (grid 1024 = bh x 16ns, 64-iter loop, unroll 2, row-major krb).
__global__ __launch_bounds__(256, 4) void kvpart_kernel(
    const u16* __restrict__ krb, const u16* __restrict__ xb,
    float* __restrict__ partial, float* __restrict__ kmr)
{
  __shared__ float red[2][64][65];   // odd stride: conflict-free lane columns
  const int t = threadIdx.x;
  const int l = t & 63;
  const int nsub = t >> 6;
  const int dg = l >> 3, eg = l & 7;
  const int d0 = dg*8, e0 = eg*8;
  const int blk = blockIdx.x;
  const int bh = blk >> 4;
  const int ns = blk & 15;
  const int b = bh >> 4, h = bh & 15;

  float acc[8][8];
  #pragma unroll
  for (int i=0;i<8;++i)
    #pragma unroll
    for (int j=0;j<8;++j) acc[i][j]=0.f;
  float ksum[8];
  #pragma unroll
  for (int i=0;i<8;++i) ksum[i]=0.f;

  const size_t base = ((size_t)b*4096 + ns*256 + nsub*64) * 1024 + h*64;
  #pragma unroll 2
  for (int it = 0; it < 64; ++it) {
    const size_t roff = base + (size_t)it*1024;
    const s16x8 k8 = *(const s16x8*)(krb + roff + d0);
    const s16x8 v8 = *(const s16x8*)(xb + roff + e0);
    float kf[8], vf[8];
    #pragma unroll
    for (int i=0;i<8;++i){ kf[i]=bf2f((u16)k8[i]); vf[i]=bf2f((u16)v8[i]); }
    #pragma unroll
    for (int i=0;i<8;++i){
      ksum[i]+=kf[i];
      #pragma unroll
      for (int j=0;j<8;++j) acc[i][j] += kf[i]*vf[j];
    }
  }

  if (nsub >= 2) {
    #pragma unroll
    for (int i=0;i<8;++i)
      #pragma unroll
      for (int j=0;j<8;++j) red[nsub-2][l][i*8+j] = acc[i][j];
  }
  __syncthreads();
  if (nsub < 2) {
    #pragma unroll
    for (int i=0;i<8;++i)
      #pragma unroll
      for (int j=0;j<8;++j) acc[i][j] += red[nsub][l][i*8+j];
  }
  __syncthreads();
  if (nsub == 1) {
    #pragma unroll
    for (int i=0;i<8;++i)
      #pragma unroll
      for (int j=0;j<8;++j) red[0][l][i*8+j] = acc[i][j];
  }
  __syncthreads();
  if (nsub == 0) {
    float* dst = partial + ((size_t)ns*64 + bh)*4096 + d0*64 + e0;
    #pragma unroll
    for (int i=0;i<8;++i) {
      f32x4 lo, hi;
      #pragma unroll
      for (int j=0;j<4;++j) { lo[j] = acc[i][j] + red[0][l][i*8+j];
                              hi[j] = acc[i][j+4] + red[0][l][i*8+j+4]; }
      *(f32x4*)(dst + i*64)     = lo;
      *(f32x4*)(dst + i*64 + 4) = hi;
    }
  }
  if (eg == 0) {
    #pragma unroll
    for (int i=0;i<8;++i)
      atomicAdd(kmr + bh*64 + d0 + i, ksum[i] * (1.f/4096.f));
  }
}

// ---------------- kernel 2b: sum 16 partial slices, *1/n, transpose -> kvbT bf16 ----
__global__ __launch_bounds__(256) void kvred_kernel(
    const float* __restrict__ partial, u16* __restrict__ kvbT)
{
  __shared__ float s[4096];
  const int bh = blockIdx.x;
  const int t = threadIdx.x;
  f32x4 a0={0,0,0,0}, a1={0,0,0,0}, a2={0,0,0,0}, a3={0,0,0,0};
  #pragma unroll
  for (int sl=0; sl<16; ++sl) {
    const f32x4* p = (const f32x4*)(partial + ((size_t)sl*64 + bh)*4096 + t*16);
    a0 += p[0]; a1 += p[1]; a2 += p[2]; a3 += p[3];
  }
  ((f32x4*)s)[t*4+0]=a0; ((f32x4*)s)[t*4+1]=a1;
  ((f32x4*)s)[t*4+2]=a2; ((f32x4*)s)[t*4+3]=a3;
  __syncthreads();
  const float inv_n = 1.f / 4096.f;
  s16x8 o0, o1;
  #pragma unroll
  for (int j=0;j<8;++j) {
    o0[j] = (short)f2bf(s[((t&3)*16 + j)*64 + (t>>2)] * inv_n);
    o1[j] = (short)f2bf(s[((t&3)*16 + 8 + j)*64 + (t>>2)] * inv_n);
  }
  *(s16x8*)(kvbT + (size_t)bh*4096 + t*16) = o0;
  *(s16x8*)(kvbT + (size_t)bh*4096 + t*16 + 8) = o1;
}

// ---------------- kernel 3: attn MFMA + fused z + z scale + fused pe conv ----------
// R9-exact except pe reads xb (bf16) instead of x (fp32) -- halves pe traffic.
__global__ __launch_bounds__(256) void attn_kernel(
    const u16* __restrict__ qrb, const u16* __restrict__ kvbT,
    const float* __restrict__ kmr, const u16* __restrict__ xb,
    const float* __restrict__ lw, const float* __restrict__ lb,
    float* __restrict__ out)
{
  __shared__ __align__(16) unsigned char As[16384]; // 128 rows x 128B
  __shared__ __align__(16) unsigned char Bs[8192];  // 64 rows x 128B
  __shared__ float lws[192], lbs[64];
  __shared__ float kms[64];
  __shared__ float zs[128];
  const int t = threadIdx.x, l = t & 63, w = t >> 6;
  const int m0 = blockIdx.x * 128;
  const int h = blockIdx.y, b = blockIdx.z;
  const size_t qbase = ((size_t)b*4096 + m0) * 1024 + h*64;   // row-major
  const u16* kvsrc = kvbT + ((size_t)(b*16 + h) << 12);

  #pragma unroll
  for (int i = 0; i < 4; ++i) {
    const int jc   = i*256 + t;
    const int row  = jc >> 3;                          // 0..127
    const int cole = (((jc & 7) << 4) ^ ((row & 7) << 4)) >> 1;
    const int ldsoff = (i*256 + w*64) * 16;
    __builtin_amdgcn_global_load_lds(
      (const __attribute__((address_space(1))) void*)(qrb + qbase + (size_t)row*1024 + cole),
      (__attribute__((address_space(3))) void*)(As + ldsoff), 16, 0, 0);
  }
  #pragma unroll
  for (int i = 0; i < 2; ++i) {
    const int jc   = i*256 + t;
    const int row  = jc >> 3;                          // e: 0..63
    const int cole = (((jc & 7) << 4) ^ ((row & 7) << 4)) >> 1;
    const int ldsoff = (i*256 + w*64) * 16;
    __builtin_amdgcn_global_load_lds(
      (const __attribute__((address_space(1))) void*)(kvsrc + (size_t)row*64 + cole),
      (__attribute__((address_space(3))) void*)(Bs + ldsoff), 16, 0, 0);
  }
  if (t < 192) lws[t] = lw[h*192 + t];
  if (t >= 192)  lbs[t-192] = lb[h*64 + (t-192)];
  if (t < 64) kms[t] = kmr[(b*16 + h)*64 + t];
  __syncthreads();

  // fused z: row r = t>>1, d-half = t&1; q from swizzled As
  {
    const int r = t >> 1, half = t & 1;
    const int swz = (r & 7) << 4;
    float zp = 0.f;
    #pragma unroll
    for (int c = 0; c < 4; ++c) {
      const int kb = half*64 + c*16;
      const s16x8 qv = *(const s16x8*)(As + r*128 + (kb ^ swz));
      #pragma unroll
      for (int j = 0; j < 8; ++j) zp += bf2f((u16)qv[j]) * kms[half*32 + c*8 + j];
    }
    zp += __shfl_xor(zp, 1);
    if (!half) zs[r] = 1.f / (zp + 1e-6f);
  }

  f32x4 acc[2][4];
  #pragma unroll
  for (int a = 0; a < 2; ++a)
    #pragma unroll
    for (int c = 0; c < 4; ++c) acc[a][c] = (f32x4){0.f,0.f,0.f,0.f};

  #pragma unroll
  for (int ks = 0; ks < 2; ++ks) {
    const int kbyte = ks*64 + ((l >> 4) << 4);
    s16x8 af[2], bf[4];
    #pragma unroll
    for (int mi = 0; mi < 2; ++mi) {
      const int r = w*32 + mi*16 + (l & 15);
      af[mi] = *(const s16x8*)(As + r*128 + (kbyte ^ ((r & 7) << 4)));
    }
    #pragma unroll
    for (int ni = 0; ni < 4; ++ni) {
      const int r = ni*16 + (l & 15);
      bf[ni] = *(const s16x8*)(Bs + r*128 + (kbyte ^ ((r & 7) << 4)));
    }
    #pragma unroll
    for (int mi = 0; mi < 2; ++mi)
      #pragma unroll
      for (int ni = 0; ni < 4; ++ni)
        acc[mi][ni] = __builtin_amdgcn_mfma_f32_16x16x32_bf16(af[mi], bf[ni], acc[mi][ni], 0, 0, 0);
  }
  __syncthreads();   // zs ready for epilogue

  // epilogue: out = acc * z[row] + pe(xb)
  #pragma unroll
  for (int mi = 0; mi < 2; ++mi) {
    #pragma unroll
    for (int j = 0; j < 4; ++j) {
      const int rowm = m0 + w*32 + mi*16 + ((l >> 4) << 2) + j;
      const float zr = zs[rowm - m0];
      const size_t rbase = ((size_t)b*4096 + rowm)*1024;
      #pragma unroll
      for (int ni = 0; ni < 4; ++ni) {
        const int cl = ni*16 + (l & 15);       // in-head channel 0..63
        const int c = h*64 + cl;
        float pe = lbs[cl] + bf2f(xb[rbase + c])*lws[cl*3+1];
        if (rowm > 0)    pe += bf2f(xb[rbase - 1024 + c])*lws[cl*3];
        if (rowm < 4095) pe += bf2f(xb[rbase + 1024 + c])*lws[cl*3+2];
        out[rbase + c] = acc[mi][ni][j]*zr + pe;
      }
    }
  }
}

extern "C" void kernel_launch(void* const* d_in, const int* in_sizes, int n_in,
                              void* d_out, int out_size, void* d_ws, size_t ws_size,
                              hipStream_t stream) {
  const float* x   = (const float*)d_in[0];
  const float* Wqk = (const float*)d_in[1];
  const float* bqk = (const float*)d_in[2];
  const float* lw  = (const float*)d_in[3];
  const float* lb  = (const float*)d_in[4];
  float* out = (float*)d_out;

  char* ws = (char*)d_ws;
  u16* xb    = (u16*)(ws);                       // 33.55 MB  x bf16
  u16* qrb   = (u16*)(ws + 33554432ull);         // 33.55 MB  q_rope bf16 (row-major)
  u16* krb   = (u16*)(ws + 67108864ull);         // 33.55 MB  k_rope bf16 (row-major)
  u16* wb    = (u16*)(ws + 100663296ull);        //  4.19 MB  W bf16
  float* kmr = (float*)(ws + 104857600ull);      // 16 KB     fp32
  float* ctab= (float*)(ws + 104874368ull);      //  2 KB
  float* stab= (float*)(ws + 104876416ull);      //  2 KB
  u16* kvbT  = (u16*)(ws + 104878464ull);        // 0.5 MB    kv^T bf16
  // kv partials (16.7 MB fp32) live in d_out scratch; attn overwrites all of out later.
  float* partial = out;

  hipMemsetAsync(kmr, 0, 16384ull, stream);      // atomic target only
  hipLaunchKernelGGL(trig_kernel, dim3(1), dim3(512), 0, stream, ctab, stab);
  hipLaunchKernelGGL(cast_kernel, dim3(2048), dim3(256), 0, stream, x, Wqk, xb, wb);
  hipLaunchKernelGGL(gemm_kernel, dim3(64, 8), dim3(512), 0, stream, xb, wb, bqk, ctab, stab, qrb, krb);
  hipLaunchKernelGGL(kvpart_kernel, dim3(1024), dim3(256), 0, stream, krb, xb, partial, kmr);
  hipLaunchKernelGGL(kvred_kernel, dim3(64), dim3(256), 0, stream, partial, kvbT);
  hipLaunchKernelGGL(attn_kernel, dim3(32, 16, 4), dim3(256), 0, stream, qrb, kvbT, kmr, xb, lw, lb, out);
}

// Round 14
// 209.752 us; speedup vs baseline: 1.5357x; 1.1474x over previous
//
#include <hip/hip_runtime.h>
#include <hip/hip_bf16.h>
#include <math.h>

typedef unsigned short u16;
typedef __attribute__((ext_vector_type(8))) short s16x8;
typedef __attribute__((ext_vector_type(4))) float f32x4;

#define B_ 4
#define N_ 4096
#define C_ 1024
#define M_ (B_*N_)
#define NT_ 16   // K / 64

__device__ __forceinline__ u16 f2bf(float f) {
  unsigned u = __builtin_bit_cast(unsigned, f);
  u = u + 0x7fffu + ((u >> 16) & 1u);
  return (u16)(u >> 16);
}
__device__ __forceinline__ float bf2f(u16 h) {
  unsigned u = ((unsigned)h) << 16;
  return __builtin_bit_cast(float, u);
}

// ---------------- kernel T: one-time rope trig table (512 pairs) ----------------
__global__ void trig_kernel(float* __restrict__ ctab, float* __restrict__ stab) {
  const int i = threadIdx.x;   // 0..511
  const float theta = powf(10000.f, -(float)i * (1.f/512.f));
  ctab[i] = cosf(theta);
  stab[i] = sinf(theta);
}

// ---------------- kernel 0: fp32 -> bf16 precast of x and W ----------------
__global__ __launch_bounds__(256) void cast_kernel(
    const float* __restrict__ x, const float* __restrict__ w,
    u16* __restrict__ xb, u16* __restrict__ wb)
{
  const int NX4 = M_*C_/4;     // 4194304
  const int NW4 = 2048*C_/4;   // 524288
  int tid = blockIdx.x*256 + threadIdx.x;
  int stride = gridDim.x*256;
  for (int i = tid; i < NX4; i += stride) {
    f32x4 v = ((const f32x4*)x)[i];
    ushort4 o;
    o.x = f2bf(v[0]); o.y = f2bf(v[1]); o.z = f2bf(v[2]); o.w = f2bf(v[3]);
    ((ushort4*)xb)[i] = o;
  }
  for (int i = tid; i < NW4; i += stride) {
    f32x4 v = ((const f32x4*)w)[i];
    ushort4 o;
    o.x = f2bf(v[0]); o.y = f2bf(v[1]); o.z = f2bf(v[2]); o.w = f2bf(v[3]);
    ((ushort4*)wb)[i] = o;
  }
}

// ---------------- kernel 1: qk GEMM + bias + elu+1 + ROPE -> q_rope,k_rope ----
// R9 core (verified). NEW epilogue: rope'd pairs staged to LDS (dead after
// K-loop), then fully-coalesced 16B stores -> kills the 2.4x write-allocate
// amplification (WRITE_SIZE 160MB -> ~75MB).
__global__ __launch_bounds__(512, 2) void gemm_kernel(
    const u16* __restrict__ xb, const u16* __restrict__ wb,
    const float* __restrict__ bqk,
    const float* __restrict__ ctab, const float* __restrict__ stab,
    u16* __restrict__ qrb, u16* __restrict__ krb)
{
  __shared__ __align__(16) unsigned char SH[131072];
  unsigned char (*As)[32768] = (unsigned char (*)[32768])SH;           // 2 bufs
  unsigned char (*Bs)[32768] = (unsigned char (*)[32768])(SH + 65536); // 2 bufs
  const int t = threadIdx.x;             // 0..511
  const int l = t & 63;
  const int w = t >> 6;                  // 0..7
  const int wm = w >> 2, wn = w & 3;     // 2M x 4N
  const int m0 = blockIdx.x * 256;
  const int n0 = blockIdx.y * 256;

  f32x4 acc[8][4];
  #pragma unroll
  for (int a = 0; a < 8; ++a)
    #pragma unroll
    for (int b = 0; b < 4; ++b) acc[a][b] = (f32x4){0.f,0.f,0.f,0.f};

  const int s_cole = ((t & 7) ^ ((t >> 3) & 7)) << 3;      // element offset 0..56
  const size_t a_base = (size_t)(m0 + (t >> 3)) * 1024 + s_cole;
  const size_t b_base = (size_t)(n0 + (t >> 3)) * 1024 + s_cole;

  #define GLA(buf, kt, i_)                                                     \
    __builtin_amdgcn_global_load_lds(                                          \
      (const __attribute__((address_space(1))) void*)(xb + a_base + (size_t)(i_)*65536 + (kt)*64), \
      (__attribute__((address_space(3))) void*)(&As[buf][((i_)*512 + w*64)*16]), 16, 0, 0)
  #define GLB(buf, kt, i_)                                                     \
    __builtin_amdgcn_global_load_lds(                                          \
      (const __attribute__((address_space(1))) void*)(wb + b_base + (size_t)(i_)*65536 + (kt)*64), \
      (__attribute__((address_space(3))) void*)(&Bs[buf][((i_)*512 + w*64)*16]), 16, 0, 0)

  GLA(0,0,0); GLA(0,0,1); GLA(0,0,2); GLA(0,0,3);
  GLB(0,0,0); GLB(0,0,1); GLB(0,0,2); GLB(0,0,3);
  asm volatile("s_waitcnt vmcnt(0)" ::: "memory");
  __builtin_amdgcn_s_barrier();

  for (int kt = 0; kt < NT_; ++kt) {
    const int cur = kt & 1;
    const int nx = cur ^ 1;
    const unsigned char* Ab = As[cur];
    const unsigned char* Bb = Bs[cur];
    s16x8 bfr[4][2];
    #pragma unroll
    for (int p = 0; p < 4; ++p) {
      s16x8 af[2][2];
      #pragma unroll
      for (int f = 0; f < 2; ++f) {
        const int r = wm*128 + (2*p + f)*16 + (l & 15);
        #pragma unroll
        for (int ks = 0; ks < 2; ++ks) {
          const int kbyte = ks*64 + ((l >> 4) << 4);
          af[f][ks] = *(const s16x8*)(Ab + r*128 + (kbyte ^ ((r & 7) << 4)));
        }
      }
      if (p == 0) {
        #pragma unroll
        for (int nf = 0; nf < 4; ++nf) {
          const int r = wn*64 + nf*16 + (l & 15);
          #pragma unroll
          for (int ks = 0; ks < 2; ++ks) {
            const int kbyte = ks*64 + ((l >> 4) << 4);
            bfr[nf][ks] = *(const s16x8*)(Bb + r*128 + (kbyte ^ ((r & 7) << 4)));
          }
        }
      }
      if (kt + 1 < NT_) {
        if (p == 0) { GLB(nx, kt+1, 0); GLB(nx, kt+1, 1); GLB(nx, kt+1, 2); GLB(nx, kt+1, 3); }
        if (p == 1) { GLA(nx, kt+1, 0); GLA(nx, kt+1, 2); }
        if (p == 2) { GLA(nx, kt+1, 1); GLA(nx, kt+1, 3); }
      }
      __builtin_amdgcn_s_barrier();
      __builtin_amdgcn_s_setprio(1);
      #pragma unroll
      for (int f = 0; f < 2; ++f)
        #pragma unroll
        for (int nf = 0; nf < 4; ++nf)
          #pragma unroll
          for (int ks = 0; ks < 2; ++ks)
            acc[2*p + f][nf] = __builtin_amdgcn_mfma_f32_16x16x32_bf16(
                af[f][ks], bfr[nf][ks], acc[2*p + f][nf], 0, 0, 0);
      __builtin_amdgcn_s_setprio(0);
      if (p == 1) {
        if (kt < NT_ - 1) asm volatile("s_waitcnt vmcnt(6)" ::: "memory");
        else              asm volatile("s_waitcnt vmcnt(0)" ::: "memory");
      }
      if (p == 3 && kt + 1 < NT_) {
        asm volatile("s_waitcnt vmcnt(2)" ::: "memory");
      }
      __builtin_amdgcn_s_barrier();
    }
  }
  #undef GLA
  #undef GLB

  // ---- epilogue phase 1: bias + elu+1 + rope, pack pairs as u32 into LDS ----
  // LDS tile [256 rows][512B], byte ^ ((row&7)<<4) swizzle (bijective in-row).
  #pragma unroll
  for (int nf = 0; nf < 4; ++nf) {
    const int lcol = wn*64 + nf*16 + (l & 15);       // 0..255 (parity == l&1)
    const int col = n0 + lcol;
    const float bias = bqk[col];
    const int cc = col & 1023;
    const float cn = ctab[cc >> 1];
    const float sn = stab[cc >> 1];
    const int lcolp2 = (lcol & ~1) * 2;              // pair byte offset in row
    #pragma unroll
    for (int mf = 0; mf < 8; ++mf) {
      #pragma unroll
      for (int j = 0; j < 4; ++j) {
        const int rloc = wm*128 + mf*16 + ((l >> 4) << 2) + j;
        float v = acc[mf][nf][j] + bias;
        v = (v > 0.f) ? (v + 1.f) : __expf(v);      // elu(v)+1
        const float vp = __shfl_xor(v, 1);          // partner column (elu'd)
        if (((l & 1) == 0) == (mf < 4)) {           // split duty: even->mf0-3
          const float e = (l & 1) ? vp : v;         // even-col value
          const float o = (l & 1) ? v : vp;         // odd-col value
          const unsigned pack = (unsigned)f2bf(cn*e - sn*o)
                              | ((unsigned)f2bf(sn*e + cn*o) << 16);
          *(unsigned*)(SH + rloc*512 + (lcolp2 ^ ((rloc & 7) << 4))) = pack;
        }
      }
    }
  }
  __syncthreads();
  // ---- epilogue phase 2: coalesced 16B stores (full rows) ----
  {
    u16* dst = (n0 < 1024) ? qrb : krb;
    const int colbase = n0 & 1023;
    #pragma unroll
    for (int it = 0; it < 16; ++it) {
      const int chunk = it*512 + t;      // 8192 chunks of 16B
      const int r = chunk >> 5;          // row 0..255
      const int c = chunk & 31;          // 16B chunk in row (8 cols)
      const s16x8 val = *(const s16x8*)(SH + r*512 + ((c ^ (r & 7)) << 4));
      *(s16x8*)(dst + (size_t)(m0 + r)*1024 + colbase + c*8) = val;
    }
  }
}

// ---------------- kernel 2: kv partials: 8d x 8e per thread, 16 n-slices ----------
// R13 core; kmr atomics replaced by per-slice ksum -> ksump (reduced in kvred).
__global__ __launch_bounds__(256, 4) void kvpart_kernel(
    const u16* __restrict__ krb, const u16* __restrict__ xb,
    float* __restrict__ partial, float* __restrict__ ksump)
{
  __shared__ float red[2][64][65];   // odd stride: conflict-free lane columns
  __shared__ float ksred[4][64];
  const int t = threadIdx.x;
  const int l = t & 63;
  const int nsub = t >> 6;
  const int dg = l >> 3, eg = l & 7;
  const int d0 = dg*8, e0 = eg*8;
  const int blk = blockIdx.x;
  const int bh = blk >> 4;
  const int ns = blk & 15;
  const int b = bh >> 4, h = bh & 15;

  float acc[8][8];
  #pragma unroll
  for (int i=0;i<8;++i)
    #pragma unroll
    for (int j=0;j<8;++j) acc[i][j]=0.f;
  float ksum[8];
  #pragma unroll
  for (int i=0;i<8;++i) ksum[i]=0.f;

  const size_t base = ((size_t)b*4096 + ns*256 + nsub*64) * 1024 + h*64;
  #pragma unroll 2
  for (int it = 0; it < 64; ++it) {
    const size_t roff = base + (size_t)it*1024;
    const s16x8 k8 = *(const s16x8*)(krb + roff + d0);
    const s16x8 v8 = *(const s16x8*)(xb + roff + e0);
    float kf[8], vf[8];
    #pragma unroll
    for (int i=0;i<8;++i){ kf[i]=bf2f((u16)k8[i]); vf[i]=bf2f((u16)v8[i]); }
    #pragma unroll
    for (int i=0;i<8;++i){
      ksum[i]+=kf[i];
      #pragma unroll
      for (int j=0;j<8;++j) acc[i][j] += kf[i]*vf[j];
    }
  }

  if (eg == 0) {
    #pragma unroll
    for (int i=0;i<8;++i) ksred[nsub][d0+i] = ksum[i];
  }
  if (nsub >= 2) {
    #pragma unroll
    for (int i=0;i<8;++i)
      #pragma unroll
      for (int j=0;j<8;++j) red[nsub-2][l][i*8+j] = acc[i][j];
  }
  __syncthreads();
  if (t < 64) {
    const float s4 = ksred[0][t]+ksred[1][t]+ksred[2][t]+ksred[3][t];
    ksump[((size_t)ns*64 + bh)*64 + t] = s4;
  }
  if (nsub < 2) {
    #pragma unroll
    for (int i=0;i<8;++i)
      #pragma unroll
      for (int j=0;j<8;++j) acc[i][j] += red[nsub][l][i*8+j];
  }
  __syncthreads();
  if (nsub == 1) {
    #pragma unroll
    for (int i=0;i<8;++i)
      #pragma unroll
      for (int j=0;j<8;++j) red[0][l][i*8+j] = acc[i][j];
  }
  __syncthreads();
  if (nsub == 0) {
    float* dst = partial + ((size_t)ns*64 + bh)*4096 + d0*64 + e0;
    #pragma unroll
    for (int i=0;i<8;++i) {
      f32x4 lo, hi;
      #pragma unroll
      for (int j=0;j<4;++j) { lo[j] = acc[i][j] + red[0][l][i*8+j];
                              hi[j] = acc[i][j+4] + red[0][l][i*8+j+4]; }
      *(f32x4*)(dst + i*64)     = lo;
      *(f32x4*)(dst + i*64 + 4) = hi;
    }
  }
}

// ---------------- kernel 2b: sum 16 slices, *1/n, transpose -> kvbT bf16; kmr ----
__global__ __launch_bounds__(256) void kvred_kernel(
    const float* __restrict__ partial, const float* __restrict__ ksump,
    u16* __restrict__ kvbT, float* __restrict__ kmr)
{
  __shared__ float s[4096];
  const int bh = blockIdx.x;
  const int t = threadIdx.x;
  const float inv_n = 1.f / 4096.f;
  f32x4 a0={0,0,0,0}, a1={0,0,0,0}, a2={0,0,0,0}, a3={0,0,0,0};
  #pragma unroll
  for (int sl=0; sl<16; ++sl) {
    const f32x4* p = (const f32x4*)(partial + ((size_t)sl*64 + bh)*4096 + t*16);
    a0 += p[0]; a1 += p[1]; a2 += p[2]; a3 += p[3];
  }
  ((f32x4*)s)[t*4+0]=a0; ((f32x4*)s)[t*4+1]=a1;
  ((f32x4*)s)[t*4+2]=a2; ((f32x4*)s)[t*4+3]=a3;
  if (t < 64) {
    float ks = 0.f;
    #pragma unroll
    for (int sl = 0; sl < 16; ++sl) ks += ksump[((size_t)sl*64 + bh)*64 + t];
    kmr[bh*64 + t] = ks * inv_n;
  }
  __syncthreads();
  s16x8 o0, o1;
  #pragma unroll
  for (int j=0;j<8;++j) {
    o0[j] = (short)f2bf(s[((t&3)*16 + j)*64 + (t>>2)] * inv_n);
    o1[j] = (short)f2bf(s[((t&3)*16 + 8 + j)*64 + (t>>2)] * inv_n);
  }
  *(s16x8*)(kvbT + (size_t)bh*4096 + t*16) = o0;
  *(s16x8*)(kvbT + (size_t)bh*4096 + t*16 + 8) = o1;
}

// ---------------- kernel 3: attn MFMA + fused z + z scale + fused pe conv ----------
__global__ __launch_bounds__(256) void attn_kernel(
    const u16* __restrict__ qrb, const u16* __restrict__ kvbT,
    const float* __restrict__ kmr, const u16* __restrict__ xb,
    const float* __restrict__ lw, const float* __restrict__ lb,
    float* __restrict__ out)
{
  __shared__ __align__(16) unsigned char As[16384]; // 128 rows x 128B
  __shared__ __align__(16) unsigned char Bs[8192];  // 64 rows x 128B
  __shared__ float lws[192], lbs[64];
  __shared__ float kms[64];
  __shared__ float zs[128];
  const int t = threadIdx.x, l = t & 63, w = t >> 6;
  const int m0 = blockIdx.x * 128;
  const int h = blockIdx.y, b = blockIdx.z;
  const size_t qbase = ((size_t)b*4096 + m0) * 1024 + h*64;   // row-major
  const u16* kvsrc = kvbT + ((size_t)(b*16 + h) << 12);

  #pragma unroll
  for (int i = 0; i < 4; ++i) {
    const int jc   = i*256 + t;
    const int row  = jc >> 3;                          // 0..127
    const int cole = (((jc & 7) << 4) ^ ((row & 7) << 4)) >> 1;
    const int ldsoff = (i*256 + w*64) * 16;
    __builtin_amdgcn_global_load_lds(
      (const __attribute__((address_space(1))) void*)(qrb + qbase + (size_t)row*1024 + cole),
      (__attribute__((address_space(3))) void*)(As + ldsoff), 16, 0, 0);
  }
  #pragma unroll
  for (int i = 0; i < 2; ++i) {
    const int jc   = i*256 + t;
    const int row  = jc >> 3;                          // e: 0..63
    const int cole = (((jc & 7) << 4) ^ ((row & 7) << 4)) >> 1;
    const int ldsoff = (i*256 + w*64) * 16;
    __builtin_amdgcn_global_load_lds(
      (const __attribute__((address_space(1))) void*)(kvsrc + (size_t)row*64 + cole),
      (__attribute__((address_space(3))) void*)(Bs + ldsoff), 16, 0, 0);
  }
  if (t < 192) lws[t] = lw[h*192 + t];
  if (t >= 192)  lbs[t-192] = lb[h*64 + (t-192)];
  if (t < 64) kms[t] = kmr[(b*16 + h)*64 + t];
  __syncthreads();

  // fused z: row r = t>>1, d-half = t&1; q from swizzled As
  {
    const int r = t >> 1, half = t & 1;
    const int swz = (r & 7) << 4;
    float zp = 0.f;
    #pragma unroll
    for (int c = 0; c < 4; ++c) {
      const int kb = half*64 + c*16;
      const s16x8 qv = *(const s16x8*)(As + r*128 + (kb ^ swz));
      #pragma unroll
      for (int j = 0; j < 8; ++j) zp += bf2f((u16)qv[j]) * kms[half*32 + c*8 + j];
    }
    zp += __shfl_xor(zp, 1);
    if (!half) zs[r] = 1.f / (zp + 1e-6f);
  }

  f32x4 acc[2][4];
  #pragma unroll
  for (int a = 0; a < 2; ++a)
    #pragma unroll
    for (int c = 0; c < 4; ++c) acc[a][c] = (f32x4){0.f,0.f,0.f,0.f};

  #pragma unroll
  for (int ks = 0; ks < 2; ++ks) {
    const int kbyte = ks*64 + ((l >> 4) << 4);
    s16x8 af[2], bf[4];
    #pragma unroll
    for (int mi = 0; mi < 2; ++mi) {
      const int r = w*32 + mi*16 + (l & 15);
      af[mi] = *(const s16x8*)(As + r*128 + (kbyte ^ ((r & 7) << 4)));
    }
    #pragma unroll
    for (int ni = 0; ni < 4; ++ni) {
      const int r = ni*16 + (l & 15);
      bf[ni] = *(const s16x8*)(Bs + r*128 + (kbyte ^ ((r & 7) << 4)));
    }
    #pragma unroll
    for (int mi = 0; mi < 2; ++mi)
      #pragma unroll
      for (int ni = 0; ni < 4; ++ni)
        acc[mi][ni] = __builtin_amdgcn_mfma_f32_16x16x32_bf16(af[mi], bf[ni], acc[mi][ni], 0, 0, 0);
  }
  __syncthreads();   // zs ready for epilogue

  // epilogue: out = acc * z[row] + pe(xb)
  #pragma unroll
  for (int mi = 0; mi < 2; ++mi) {
    #pragma unroll
    for (int j = 0; j < 4; ++j) {
      const int rowm = m0 + w*32 + mi*16 + ((l >> 4) << 2) + j;
      const float zr = zs[rowm - m0];
      const size_t rbase = ((size_t)b*4096 + rowm)*1024;
      #pragma unroll
      for (int ni = 0; ni < 4; ++ni) {
        const int cl = ni*16 + (l & 15);       // in-head channel 0..63
        const int c = h*64 + cl;
        float pe = lbs[cl] + bf2f(xb[rbase + c])*lws[cl*3+1];
        if (rowm > 0)    pe += bf2f(xb[rbase - 1024 + c])*lws[cl*3];
        if (rowm < 4095) pe += bf2f(xb[rbase + 1024 + c])*lws[cl*3+2];
        out[rbase + c] = acc[mi][ni][j]*zr + pe;
      }
    }
  }
}

extern "C" void kernel_launch(void* const* d_in, const int* in_sizes, int n_in,
                              void* d_out, int out_size, void* d_ws, size_t ws_size,
                              hipStream_t stream) {
  const float* x   = (const float*)d_in[0];
  const float* Wqk = (const float*)d_in[1];
  const float* bqk = (const float*)d_in[2];
  const float* lw  = (const float*)d_in[3];
  const float* lb  = (const float*)d_in[4];
  float* out = (float*)d_out;

  char* ws = (char*)d_ws;
  u16* xb    = (u16*)(ws);                       // 33.55 MB  x bf16
  u16* qrb   = (u16*)(ws + 33554432ull);         // 33.55 MB  q_rope bf16 (row-major)
  u16* krb   = (u16*)(ws + 67108864ull);         // 33.55 MB  k_rope bf16 (row-major)
  u16* wb    = (u16*)(ws + 100663296ull);        //  4.19 MB  W bf16
  float* kmr = (float*)(ws + 104857600ull);      // 16 KB     fp32
  float* ctab= (float*)(ws + 104874368ull);      //  2 KB
  float* stab= (float*)(ws + 104876416ull);      //  2 KB
  u16* kvbT  = (u16*)(ws + 104878464ull);        // 0.5 MB    kv^T bf16
  // kv partials (16.7 MB) + ksump (256 KB) live in d_out scratch;
  // attn overwrites all of out afterwards (stream-ordered).
  float* partial = out;
  float* ksump   = out + 4194304;

  hipLaunchKernelGGL(trig_kernel, dim3(1), dim3(512), 0, stream, ctab, stab);
  hipLaunchKernelGGL(cast_kernel, dim3(2048), dim3(256), 0, stream, x, Wqk, xb, wb);
  hipLaunchKernelGGL(gemm_kernel, dim3(64, 8), dim3(512), 0, stream, xb, wb, bqk, ctab, stab, qrb, krb);
  hipLaunchKernelGGL(kvpart_kernel, dim3(1024), dim3(256), 0, stream, krb, xb, partial, ksump);
  hipLaunchKernelGGL(kvred_kernel, dim3(64), dim3(256), 0, stream, partial, ksump, kvbT, kmr);
  hipLaunchKernelGGL(attn_kernel, dim3(32, 16, 4), dim3(256), 0, stream, qrb, kvbT, kmr, xb, lw, lb, out);
}

// Round 15
// 205.760 us; speedup vs baseline: 1.5655x; 1.0194x over previous
//
#include <hip/hip_runtime.h>
#include <hip/hip_bf16.h>
#include <math.h>

typedef unsigned short u16;
typedef __attribute__((ext_vector_type(8))) short s16x8;
typedef __attribute__((ext_vector_type(4))) float f32x4;

#define B_ 4
#define N_ 4096
#define C_ 1024
#define M_ (B_*N_)
#define NT_ 16   // K / 64

__device__ __forceinline__ u16 f2bf(float f) {
  unsigned u = __builtin_bit_cast(unsigned, f);
  u = u + 0x7fffu + ((u >> 16) & 1u);
  return (u16)(u >> 16);
}
__device__ __forceinline__ float bf2f(u16 h) {
  unsigned u = ((unsigned)h) << 16;
  return __builtin_bit_cast(float, u);
}

// ---------------- kernel T: one-time rope trig table (512 pairs) ----------------
__global__ void trig_kernel(float* __restrict__ ctab, float* __restrict__ stab) {
  const int i = threadIdx.x;   // 0..511
  const float theta = powf(10000.f, -(float)i * (1.f/512.f));
  ctab[i] = cosf(theta);
  stab[i] = sinf(theta);
}

// ---------------- kernel 0: fp32 -> bf16 precast of x and W ----------------
__global__ __launch_bounds__(256) void cast_kernel(
    const float* __restrict__ x, const float* __restrict__ w,
    u16* __restrict__ xb, u16* __restrict__ wb)
{
  const int NX4 = M_*C_/4;     // 4194304
  const int NW4 = 2048*C_/4;   // 524288
  int tid = blockIdx.x*256 + threadIdx.x;
  int stride = gridDim.x*256;
  for (int i = tid; i < NX4; i += stride) {
    f32x4 v = ((const f32x4*)x)[i];
    ushort4 o;
    o.x = f2bf(v[0]); o.y = f2bf(v[1]); o.z = f2bf(v[2]); o.w = f2bf(v[3]);
    ((ushort4*)xb)[i] = o;
  }
  for (int i = tid; i < NW4; i += stride) {
    f32x4 v = ((const f32x4*)w)[i];
    ushort4 o;
    o.x = f2bf(v[0]); o.y = f2bf(v[1]); o.z = f2bf(v[2]); o.w = f2bf(v[3]);
    ((ushort4*)wb)[i] = o;
  }
}

// ---------------- kernel 1: qk GEMM + bias + elu+1 + ROPE -> q_rope,k_rope ----
// R9 dataflow, MERGED to 2 phases / 2 barriers per K-tile (was 4 phases / 8).
// Per-wave issue order per kt: [B(kt+1)x4, Ae(kt+1)x2] @phA, [Al(kt+1)x2] @phB.
// Drains: vmcnt(6)@phA-end (A-late(kt)), vmcnt(2)@phB-end (B+Ae(kt+1)).
// Coalesced LDS-transposed epilogue (R14, WRITE=65MB verified).
__global__ __launch_bounds__(512, 2) void gemm_kernel(
    const u16* __restrict__ xb, const u16* __restrict__ wb,
    const float* __restrict__ bqk,
    const float* __restrict__ ctab, const float* __restrict__ stab,
    u16* __restrict__ qrb, u16* __restrict__ krb)
{
  __shared__ __align__(16) unsigned char SH[131072];
  unsigned char (*As)[32768] = (unsigned char (*)[32768])SH;           // 2 bufs
  unsigned char (*Bs)[32768] = (unsigned char (*)[32768])(SH + 65536); // 2 bufs
  const int t = threadIdx.x;             // 0..511
  const int l = t & 63;
  const int w = t >> 6;                  // 0..7
  const int wm = w >> 2, wn = w & 3;     // 2M x 4N
  const int m0 = blockIdx.x * 256;
  const int n0 = blockIdx.y * 256;

  f32x4 acc[8][4];
  #pragma unroll
  for (int a = 0; a < 8; ++a)
    #pragma unroll
    for (int b = 0; b < 4; ++b) acc[a][b] = (f32x4){0.f,0.f,0.f,0.f};

  const int s_cole = ((t & 7) ^ ((t >> 3) & 7)) << 3;      // element offset 0..56
  const size_t a_base = (size_t)(m0 + (t >> 3)) * 1024 + s_cole;
  const size_t b_base = (size_t)(n0 + (t >> 3)) * 1024 + s_cole;

  #define GLA(buf, kt, i_)                                                     \
    __builtin_amdgcn_global_load_lds(                                          \
      (const __attribute__((address_space(1))) void*)(xb + a_base + (size_t)(i_)*65536 + (kt)*64), \
      (__attribute__((address_space(3))) void*)(&As[buf][((i_)*512 + w*64)*16]), 16, 0, 0)
  #define GLB(buf, kt, i_)                                                     \
    __builtin_amdgcn_global_load_lds(                                          \
      (const __attribute__((address_space(1))) void*)(wb + b_base + (size_t)(i_)*65536 + (kt)*64), \
      (__attribute__((address_space(3))) void*)(&Bs[buf][((i_)*512 + w*64)*16]), 16, 0, 0)

  // prologue: issue kt=0 in steady-state order [B x4, Ae(0,2), Al(1,3)];
  // drain first 6 (B+Ae), keep Al(0) in flight (drained at kt0 phA vmcnt(6)).
  GLB(0,0,0); GLB(0,0,1); GLB(0,0,2); GLB(0,0,3);
  GLA(0,0,0); GLA(0,0,2);
  GLA(0,0,1); GLA(0,0,3);
  asm volatile("s_waitcnt vmcnt(2)" ::: "memory");
  __builtin_amdgcn_s_barrier();

  for (int kt = 0; kt < NT_; ++kt) {
    const int cur = kt & 1;
    const int nx = cur ^ 1;
    const unsigned char* Ab = As[cur];
    const unsigned char* Bb = Bs[cur];

    // ================= phase A: B + A(mf0-3), stage 6, MFMA 32 =================
    if (kt + 1 < NT_) {
      GLB(nx, kt+1, 0); GLB(nx, kt+1, 1); GLB(nx, kt+1, 2); GLB(nx, kt+1, 3);
      GLA(nx, kt+1, 0); GLA(nx, kt+1, 2);          // A-early (rows 0-63,128-191)
    }
    s16x8 bfr[4][2];
    #pragma unroll
    for (int nf = 0; nf < 4; ++nf) {
      const int r = wn*64 + nf*16 + (l & 15);
      #pragma unroll
      for (int ks = 0; ks < 2; ++ks) {
        const int kbyte = ks*64 + ((l >> 4) << 4);
        bfr[nf][ks] = *(const s16x8*)(Bb + r*128 + (kbyte ^ ((r & 7) << 4)));
      }
    }
    {
      s16x8 af[4][2];
      #pragma unroll
      for (int f = 0; f < 4; ++f) {
        const int r = wm*128 + f*16 + (l & 15);
        #pragma unroll
        for (int ks = 0; ks < 2; ++ks) {
          const int kbyte = ks*64 + ((l >> 4) << 4);
          af[f][ks] = *(const s16x8*)(Ab + r*128 + (kbyte ^ ((r & 7) << 4)));
        }
      }
      __builtin_amdgcn_s_setprio(1);
      #pragma unroll
      for (int f = 0; f < 4; ++f)
        #pragma unroll
        for (int nf = 0; nf < 4; ++nf)
          #pragma unroll
          for (int ks = 0; ks < 2; ++ks)
            acc[f][nf] = __builtin_amdgcn_mfma_f32_16x16x32_bf16(
                af[f][ks], bfr[nf][ks], acc[f][nf], 0, 0, 0);
      __builtin_amdgcn_s_setprio(0);
    }
    // drain A-late(kt) (issued kt-1 phB / prologue); keep this phase's 6 in flight
    if (kt + 1 < NT_) asm volatile("s_waitcnt vmcnt(6)" ::: "memory");
    else              asm volatile("s_waitcnt vmcnt(0)" ::: "memory");
    __builtin_amdgcn_s_barrier();

    // ================= phase B: A(mf4-7), stage 2, MFMA 32 =====================
    if (kt + 1 < NT_) {
      GLA(nx, kt+1, 1); GLA(nx, kt+1, 3);          // A-late (rows 64-127,192-255)
    }
    {
      s16x8 af[4][2];
      #pragma unroll
      for (int f = 0; f < 4; ++f) {
        const int r = wm*128 + (f + 4)*16 + (l & 15);
        #pragma unroll
        for (int ks = 0; ks < 2; ++ks) {
          const int kbyte = ks*64 + ((l >> 4) << 4);
          af[f][ks] = *(const s16x8*)(Ab + r*128 + (kbyte ^ ((r & 7) << 4)));
        }
      }
      __builtin_amdgcn_s_setprio(1);
      #pragma unroll
      for (int f = 0; f < 4; ++f)
        #pragma unroll
        for (int nf = 0; nf < 4; ++nf)
          #pragma unroll
          for (int ks = 0; ks < 2; ++ks)
            acc[f + 4][nf] = __builtin_amdgcn_mfma_f32_16x16x32_bf16(
                af[f][ks], bfr[nf][ks], acc[f + 4][nf], 0, 0, 0);
      __builtin_amdgcn_s_setprio(0);
    }
    // drain B(kt+1)+A-early(kt+1) (6 oldest); keep A-late(kt+1) in flight
    if (kt + 1 < NT_) asm volatile("s_waitcnt vmcnt(2)" ::: "memory");
    __builtin_amdgcn_s_barrier();
  }
  #undef GLA
  #undef GLB

  // ---- epilogue phase 1: bias + elu+1 + rope, pack pairs as u32 into LDS ----
  #pragma unroll
  for (int nf = 0; nf < 4; ++nf) {
    const int lcol = wn*64 + nf*16 + (l & 15);       // 0..255 (parity == l&1)
    const int col = n0 + lcol;
    const float bias = bqk[col];
    const int cc = col & 1023;
    const float cn = ctab[cc >> 1];
    const float sn = stab[cc >> 1];
    const int lcolp2 = (lcol & ~1) * 2;              // pair byte offset in row
    #pragma unroll
    for (int mf = 0; mf < 8; ++mf) {
      #pragma unroll
      for (int j = 0; j < 4; ++j) {
        const int rloc = wm*128 + mf*16 + ((l >> 4) << 2) + j;
        float v = acc[mf][nf][j] + bias;
        v = (v > 0.f) ? (v + 1.f) : __expf(v);      // elu(v)+1
        const float vp = __shfl_xor(v, 1);          // partner column (elu'd)
        if (((l & 1) == 0) == (mf < 4)) {           // split duty: even->mf0-3
          const float e = (l & 1) ? vp : v;         // even-col value
          const float o = (l & 1) ? v : vp;         // odd-col value
          const unsigned pack = (unsigned)f2bf(cn*e - sn*o)
                              | ((unsigned)f2bf(sn*e + cn*o) << 16);
          *(unsigned*)(SH + rloc*512 + (lcolp2 ^ ((rloc & 7) << 4))) = pack;
        }
      }
    }
  }
  __syncthreads();
  // ---- epilogue phase 2: coalesced 16B stores (full rows) ----
  {
    u16* dst = (n0 < 1024) ? qrb : krb;
    const int colbase = n0 & 1023;
    #pragma unroll
    for (int it = 0; it < 16; ++it) {
      const int chunk = it*512 + t;      // 8192 chunks of 16B
      const int r = chunk >> 5;          // row 0..255
      const int c = chunk & 31;          // 16B chunk in row (8 cols)
      const s16x8 val = *(const s16x8*)(SH + r*512 + ((c ^ (r & 7)) << 4));
      *(s16x8*)(dst + (size_t)(m0 + r)*1024 + colbase + c*8) = val;
    }
  }
}

// ---------------- kernel 2: kv partials: 8d x 8e per thread, 16 n-slices ----------
__global__ __launch_bounds__(256, 4) void kvpart_kernel(
    const u16* __restrict__ krb, const u16* __restrict__ xb,
    float* __restrict__ partial, float* __restrict__ ksump)
{
  __shared__ float red[2][64][65];   // odd stride: conflict-free lane columns
  __shared__ float ksred[4][64];
  const int t = threadIdx.x;
  const int l = t & 63;
  const int nsub = t >> 6;
  const int dg = l >> 3, eg = l & 7;
  const int d0 = dg*8, e0 = eg*8;
  const int blk = blockIdx.x;
  const int bh = blk >> 4;
  const int ns = blk & 15;
  const int b = bh >> 4, h = bh & 15;

  float acc[8][8];
  #pragma unroll
  for (int i=0;i<8;++i)
    #pragma unroll
    for (int j=0;j<8;++j) acc[i][j]=0.f;
  float ksum[8];
  #pragma unroll
  for (int i=0;i<8;++i) ksum[i]=0.f;

  const size_t base = ((size_t)b*4096 + ns*256 + nsub*64) * 1024 + h*64;
  #pragma unroll 2
  for (int it = 0; it < 64; ++it) {
    const size_t roff = base + (size_t)it*1024;
    const s16x8 k8 = *(const s16x8*)(krb + roff + d0);
    const s16x8 v8 = *(const s16x8*)(xb + roff + e0);
    float kf[8], vf[8];
    #pragma unroll
    for (int i=0;i<8;++i){ kf[i]=bf2f((u16)k8[i]); vf[i]=bf2f((u16)v8[i]); }
    #pragma unroll
    for (int i=0;i<8;++i){
      ksum[i]+=kf[i];
      #pragma unroll
      for (int j=0;j<8;++j) acc[i][j] += kf[i]*vf[j];
    }
  }

  if (eg == 0) {
    #pragma unroll
    for (int i=0;i<8;++i) ksred[nsub][d0+i] = ksum[i];
  }
  if (nsub >= 2) {
    #pragma unroll
    for (int i=0;i<8;++i)
      #pragma unroll
      for (int j=0;j<8;++j) red[nsub-2][l][i*8+j] = acc[i][j];
  }
  __syncthreads();
  if (t < 64) {
    const float s4 = ksred[0][t]+ksred[1][t]+ksred[2][t]+ksred[3][t];
    ksump[((size_t)ns*64 + bh)*64 + t] = s4;
  }
  if (nsub < 2) {
    #pragma unroll
    for (int i=0;i<8;++i)
      #pragma unroll
      for (int j=0;j<8;++j) acc[i][j] += red[nsub][l][i*8+j];
  }
  __syncthreads();
  if (nsub == 1) {
    #pragma unroll
    for (int i=0;i<8;++i)
      #pragma unroll
      for (int j=0;j<8;++j) red[0][l][i*8+j] = acc[i][j];
  }
  __syncthreads();
  if (nsub == 0) {
    float* dst = partial + ((size_t)ns*64 + bh)*4096 + d0*64 + e0;
    #pragma unroll
    for (int i=0;i<8;++i) {
      f32x4 lo, hi;
      #pragma unroll
      for (int j=0;j<4;++j) { lo[j] = acc[i][j] + red[0][l][i*8+j];
                              hi[j] = acc[i][j+4] + red[0][l][i*8+j+4]; }
      *(f32x4*)(dst + i*64)     = lo;
      *(f32x4*)(dst + i*64 + 4) = hi;
    }
  }
}

// ---------------- kernel 2b: sum 16 slices, *1/n, transpose -> kvbT bf16; kmr ----
__global__ __launch_bounds__(256) void kvred_kernel(
    const float* __restrict__ partial, const float* __restrict__ ksump,
    u16* __restrict__ kvbT, float* __restrict__ kmr)
{
  __shared__ float s[4096];
  const int bh = blockIdx.x;
  const int t = threadIdx.x;
  const float inv_n = 1.f / 4096.f;
  f32x4 a0={0,0,0,0}, a1={0,0,0,0}, a2={0,0,0,0}, a3={0,0,0,0};
  #pragma unroll
  for (int sl=0; sl<16; ++sl) {
    const f32x4* p = (const f32x4*)(partial + ((size_t)sl*64 + bh)*4096 + t*16);
    a0 += p[0]; a1 += p[1]; a2 += p[2]; a3 += p[3];
  }
  ((f32x4*)s)[t*4+0]=a0; ((f32x4*)s)[t*4+1]=a1;
  ((f32x4*)s)[t*4+2]=a2; ((f32x4*)s)[t*4+3]=a3;
  if (t < 64) {
    float ks = 0.f;
    #pragma unroll
    for (int sl = 0; sl < 16; ++sl) ks += ksump[((size_t)sl*64 + bh)*64 + t];
    kmr[bh*64 + t] = ks * inv_n;
  }
  __syncthreads();
  s16x8 o0, o1;
  #pragma unroll
  for (int j=0;j<8;++j) {
    o0[j] = (short)f2bf(s[((t&3)*16 + j)*64 + (t>>2)] * inv_n);
    o1[j] = (short)f2bf(s[((t&3)*16 + 8 + j)*64 + (t>>2)] * inv_n);
  }
  *(s16x8*)(kvbT + (size_t)bh*4096 + t*16) = o0;
  *(s16x8*)(kvbT + (size_t)bh*4096 + t*16 + 8) = o1;
}

// ---------------- kernel 3: attn MFMA + fused z + z scale + fused pe conv ----------
__global__ __launch_bounds__(256) void attn_kernel(
    const u16* __restrict__ qrb, const u16* __restrict__ kvbT,
    const float* __restrict__ kmr, const u16* __restrict__ xb,
    const float* __restrict__ lw, const float* __restrict__ lb,
    float* __restrict__ out)
{
  __shared__ __align__(16) unsigned char As[16384]; // 128 rows x 128B
  __shared__ __align__(16) unsigned char Bs[8192];  // 64 rows x 128B
  __shared__ float lws[192], lbs[64];
  __shared__ float kms[64];
  __shared__ float zs[128];
  const int t = threadIdx.x, l = t & 63, w = t >> 6;
  const int m0 = blockIdx.x * 128;
  const int h = blockIdx.y, b = blockIdx.z;
  const size_t qbase = ((size_t)b*4096 + m0) * 1024 + h*64;   // row-major
  const u16* kvsrc = kvbT + ((size_t)(b*16 + h) << 12);

  #pragma unroll
  for (int i = 0; i < 4; ++i) {
    const int jc   = i*256 + t;
    const int row  = jc >> 3;                          // 0..127
    const int cole = (((jc & 7) << 4) ^ ((row & 7) << 4)) >> 1;
    const int ldsoff = (i*256 + w*64) * 16;
    __builtin_amdgcn_global_load_lds(
      (const __attribute__((address_space(1))) void*)(qrb + qbase + (size_t)row*1024 + cole),
      (__attribute__((address_space(3))) void*)(As + ldsoff), 16, 0, 0);
  }
  #pragma unroll
  for (int i = 0; i < 2; ++i) {
    const int jc   = i*256 + t;
    const int row  = jc >> 3;                          // e: 0..63
    const int cole = (((jc & 7) << 4) ^ ((row & 7) << 4)) >> 1;
    const int ldsoff = (i*256 + w*64) * 16;
    __builtin_amdgcn_global_load_lds(
      (const __attribute__((address_space(1))) void*)(kvsrc + (size_t)row*64 + cole),
      (__attribute__((address_space(3))) void*)(Bs + ldsoff), 16, 0, 0);
  }
  if (t < 192) lws[t] = lw[h*192 + t];
  if (t >= 192)  lbs[t-192] = lb[h*64 + (t-192)];
  if (t < 64) kms[t] = kmr[(b*16 + h)*64 + t];
  __syncthreads();

  // fused z: row r = t>>1, d-half = t&1; q from swizzled As
  {
    const int r = t >> 1, half = t & 1;
    const int swz = (r & 7) << 4;
    float zp = 0.f;
    #pragma unroll
    for (int c = 0; c < 4; ++c) {
      const int kb = half*64 + c*16;
      const s16x8 qv = *(const s16x8*)(As + r*128 + (kb ^ swz));
      #pragma unroll
      for (int j = 0; j < 8; ++j) zp += bf2f((u16)qv[j]) * kms[half*32 + c*8 + j];
    }
    zp += __shfl_xor(zp, 1);
    if (!half) zs[r] = 1.f / (zp + 1e-6f);
  }

  f32x4 acc[2][4];
  #pragma unroll
  for (int a = 0; a < 2; ++a)
    #pragma unroll
    for (int c = 0; c < 4; ++c) acc[a][c] = (f32x4){0.f,0.f,0.f,0.f};

  #pragma unroll
  for (int ks = 0; ks < 2; ++ks) {
    const int kbyte = ks*64 + ((l >> 4) << 4);
    s16x8 af[2], bf[4];
    #pragma unroll
    for (int mi = 0; mi < 2; ++mi) {
      const int r = w*32 + mi*16 + (l & 15);
      af[mi] = *(const s16x8*)(As + r*128 + (kbyte ^ ((r & 7) << 4)));
    }
    #pragma unroll
    for (int ni = 0; ni < 4; ++ni) {
      const int r = ni*16 + (l & 15);
      bf[ni] = *(const s16x8*)(Bs + r*128 + (kbyte ^ ((r & 7) << 4)));
    }
    #pragma unroll
    for (int mi = 0; mi < 2; ++mi)
      #pragma unroll
      for (int ni = 0; ni < 4; ++ni)
        acc[mi][ni] = __builtin_amdgcn_mfma_f32_16x16x32_bf16(af[mi], bf[ni], acc[mi][ni], 0, 0, 0);
  }
  __syncthreads();   // zs ready for epilogue

  // epilogue: out = acc * z[row] + pe(xb)
  #pragma unroll
  for (int mi = 0; mi < 2; ++mi) {
    #pragma unroll
    for (int j = 0; j < 4; ++j) {
      const int rowm = m0 + w*32 + mi*16 + ((l >> 4) << 2) + j;
      const float zr = zs[rowm - m0];
      const size_t rbase = ((size_t)b*4096 + rowm)*1024;
      #pragma unroll
      for (int ni = 0; ni < 4; ++ni) {
        const int cl = ni*16 + (l & 15);       // in-head channel 0..63
        const int c = h*64 + cl;
        float pe = lbs[cl] + bf2f(xb[rbase + c])*lws[cl*3+1];
        if (rowm > 0)    pe += bf2f(xb[rbase - 1024 + c])*lws[cl*3];
        if (rowm < 4095) pe += bf2f(xb[rbase + 1024 + c])*lws[cl*3+2];
        out[rbase + c] = acc[mi][ni][j]*zr + pe;
      }
    }
  }
}

extern "C" void kernel_launch(void* const* d_in, const int* in_sizes, int n_in,
                              void* d_out, int out_size, void* d_ws, size_t ws_size,
                              hipStream_t stream) {
  const float* x   = (const float*)d_in[0];
  const float* Wqk = (const float*)d_in[1];
  const float* bqk = (const float*)d_in[2];
  const float* lw  = (const float*)d_in[3];
  const float* lb  = (const float*)d_in[4];
  float* out = (float*)d_out;

  char* ws = (char*)d_ws;
  u16* xb    = (u16*)(ws);                       // 33.55 MB  x bf16
  u16* qrb   = (u16*)(ws + 33554432ull);         // 33.55 MB  q_rope bf16 (row-major)
  u16* krb   = (u16*)(ws + 67108864ull);         // 33.55 MB  k_rope bf16 (row-major)
  u16* wb    = (u16*)(ws + 100663296ull);        //  4.19 MB  W bf16
  float* kmr = (float*)(ws + 104857600ull);      // 16 KB     fp32
  float* ctab= (float*)(ws + 104874368ull);      //  2 KB
  float* stab= (float*)(ws + 104876416ull);      //  2 KB
  u16* kvbT  = (u16*)(ws + 104878464ull);        // 0.5 MB    kv^T bf16
  // kv partials (16.7 MB) + ksump (256 KB) live in d_out scratch;
  // attn overwrites all of out afterwards (stream-ordered).
  float* partial = out;
  float* ksump   = out + 4194304;

  hipLaunchKernelGGL(trig_kernel, dim3(1), dim3(512), 0, stream, ctab, stab);
  hipLaunchKernelGGL(cast_kernel, dim3(2048), dim3(256), 0, stream, x, Wqk, xb, wb);
  hipLaunchKernelGGL(gemm_kernel, dim3(64, 8), dim3(512), 0, stream, xb, wb, bqk, ctab, stab, qrb, krb);
  hipLaunchKernelGGL(kvpart_kernel, dim3(1024), dim3(256), 0, stream, krb, xb, partial, ksump);
  hipLaunchKernelGGL(kvred_kernel, dim3(64), dim3(256), 0, stream, partial, ksump, kvbT, kmr);
  hipLaunchKernelGGL(attn_kernel, dim3(32, 16, 4), dim3(256), 0, stream, qrb, kvbT, kmr, xb, lw, lb, out);
}

// Round 16
// 205.020 us; speedup vs baseline: 1.5712x; 1.0036x over previous
//
#include <hip/hip_runtime.h>
#include <hip/hip_bf16.h>
#include <math.h>

typedef unsigned short u16;
typedef __attribute__((ext_vector_type(8))) short s16x8;
typedef __attribute__((ext_vector_type(4))) float f32x4;

#define B_ 4
#define N_ 4096
#define C_ 1024
#define M_ (B_*N_)
#define NT_ 16   // K / 64

__device__ __forceinline__ u16 f2bf(float f) {
  unsigned u = __builtin_bit_cast(unsigned, f);
  u = u + 0x7fffu + ((u >> 16) & 1u);
  return (u16)(u >> 16);
}
__device__ __forceinline__ float bf2f(u16 h) {
  unsigned u = ((unsigned)h) << 16;
  return __builtin_bit_cast(float, u);
}

// ---------------- kernel T: one-time rope trig table (512 pairs) ----------------
__global__ void trig_kernel(float* __restrict__ ctab, float* __restrict__ stab) {
  const int i = threadIdx.x;   // 0..511
  const float theta = powf(10000.f, -(float)i * (1.f/512.f));
  ctab[i] = cosf(theta);
  stab[i] = sinf(theta);
}

// ---------------- kernel 0: fp32 -> bf16 precast of x and W ----------------
__global__ __launch_bounds__(256) void cast_kernel(
    const float* __restrict__ x, const float* __restrict__ w,
    u16* __restrict__ xb, u16* __restrict__ wb)
{
  const int NX4 = M_*C_/4;     // 4194304
  const int NW4 = 2048*C_/4;   // 524288
  int tid = blockIdx.x*256 + threadIdx.x;
  int stride = gridDim.x*256;
  for (int i = tid; i < NX4; i += stride) {
    f32x4 v = ((const f32x4*)x)[i];
    ushort4 o;
    o.x = f2bf(v[0]); o.y = f2bf(v[1]); o.z = f2bf(v[2]); o.w = f2bf(v[3]);
    ((ushort4*)xb)[i] = o;
  }
  for (int i = tid; i < NW4; i += stride) {
    f32x4 v = ((const f32x4*)w)[i];
    ushort4 o;
    o.x = f2bf(v[0]); o.y = f2bf(v[1]); o.z = f2bf(v[2]); o.w = f2bf(v[3]);
    ((ushort4*)wb)[i] = o;
  }
}

// ---------------- kernel 1: qk GEMM + bias + elu+1 + ROPE -> q_rope,k_rope ----
// R15 schedule (2 phases / 2 barriers / counted vmcnt per kt, verified ledger).
// NEW: kt-loop FULLY UNROLLED + precomputed lane-offsets -> every ds_read is
// base+offset:CONST and every gload folds kt*128 into its offset immediate.
// Targets the VALUBusy=35% address-math overhead (R15 counters).
__global__ __launch_bounds__(512, 2) void gemm_kernel(
    const u16* __restrict__ xb, const u16* __restrict__ wb,
    const float* __restrict__ bqk,
    const float* __restrict__ ctab, const float* __restrict__ stab,
    u16* __restrict__ qrb, u16* __restrict__ krb)
{
  __shared__ __align__(16) unsigned char SH[131072];   // A: [0,64K) 2 bufs; B: [64K,128K)
  const int t = threadIdx.x;             // 0..511
  const int l = t & 63;
  const int w = t >> 6;                  // 0..7
  const int wm = w >> 2, wn = w & 3;     // 2M x 4N
  const int m0 = blockIdx.x * 256;
  const int n0 = blockIdx.y * 256;

  f32x4 acc[8][4];
  #pragma unroll
  for (int a = 0; a < 8; ++a)
    #pragma unroll
    for (int b = 0; b < 4; ++b) acc[a][b] = (f32x4){0.f,0.f,0.f,0.f};

  // ---- staging sources (lane-dependent, kt folds into offset immediate) ----
  const int s_cole = ((t & 7) ^ ((t >> 3) & 7)) << 3;      // pre-swizzled col
  const u16* aS = xb + (size_t)(m0 + (t >> 3)) * 1024 + s_cole;
  const u16* bS = wb + (size_t)(n0 + (t >> 3)) * 1024 + s_cole;
  const int ldsW = w*1024;                                  // w*64*16 bytes

  #define GLA(buf, kt, i_)                                                     \
    __builtin_amdgcn_global_load_lds(                                          \
      (const __attribute__((address_space(1))) void*)(aS + (i_)*65536 + (kt)*64), \
      (__attribute__((address_space(3))) void*)(SH + (buf)*32768 + (i_)*8192 + ldsW), 16, 0, 0)
  #define GLB(buf, kt, i_)                                                     \
    __builtin_amdgcn_global_load_lds(                                          \
      (const __attribute__((address_space(1))) void*)(bS + (i_)*65536 + (kt)*64), \
      (__attribute__((address_space(3))) void*)(SH + 65536 + (buf)*32768 + (i_)*8192 + ldsW), 16, 0, 0)

  // ---- fragment ds_read lane-offsets (kt-invariant; swizzle (r&7)<<4 == (l&7)<<4) ----
  const int swzl = (l & 7) << 4;
  const int kof0 = (((l >> 4) << 4)) ^ swzl;
  const int kof1 = (64 + ((l >> 4) << 4)) ^ swzl;
  const int aFB = wm*16384 + (l & 15)*128;   // + cur*32768 + mf*2048 + kof
  const int bFB = wn*8192  + (l & 15)*128;   // + 65536 + cur*32768 + nf*2048 + kof

  // prologue: issue kt=0 in steady-state order [B x4, Ae(0,2), Al(1,3)];
  GLB(0,0,0); GLB(0,0,1); GLB(0,0,2); GLB(0,0,3);
  GLA(0,0,0); GLA(0,0,2);
  GLA(0,0,1); GLA(0,0,3);
  asm volatile("s_waitcnt vmcnt(2)" ::: "memory");
  __builtin_amdgcn_s_barrier();

  #pragma unroll
  for (int kt = 0; kt < NT_; ++kt) {
    const int cur = kt & 1;
    const int nx = cur ^ 1;

    // ================= phase A: B + A(mf0-3), stage 6, MFMA 32 =================
    if (kt + 1 < NT_) {
      GLB(nx, kt+1, 0); GLB(nx, kt+1, 1); GLB(nx, kt+1, 2); GLB(nx, kt+1, 3);
      GLA(nx, kt+1, 0); GLA(nx, kt+1, 2);          // A-early (rows 0-63,128-191)
    }
    s16x8 bfr[4][2];
    #pragma unroll
    for (int nf = 0; nf < 4; ++nf) {
      bfr[nf][0] = *(const s16x8*)(SH + 65536 + cur*32768 + bFB + nf*2048 + kof0);
      bfr[nf][1] = *(const s16x8*)(SH + 65536 + cur*32768 + bFB + nf*2048 + kof1);
    }
    {
      s16x8 af[4][2];
      #pragma unroll
      for (int f = 0; f < 4; ++f) {
        af[f][0] = *(const s16x8*)(SH + cur*32768 + aFB + f*2048 + kof0);
        af[f][1] = *(const s16x8*)(SH + cur*32768 + aFB + f*2048 + kof1);
      }
      __builtin_amdgcn_s_setprio(1);
      #pragma unroll
      for (int f = 0; f < 4; ++f)
        #pragma unroll
        for (int nf = 0; nf < 4; ++nf)
          #pragma unroll
          for (int ks = 0; ks < 2; ++ks)
            acc[f][nf] = __builtin_amdgcn_mfma_f32_16x16x32_bf16(
                af[f][ks], bfr[nf][ks], acc[f][nf], 0, 0, 0);
      __builtin_amdgcn_s_setprio(0);
    }
    if (kt + 1 < NT_) asm volatile("s_waitcnt vmcnt(6)" ::: "memory");
    else              asm volatile("s_waitcnt vmcnt(0)" ::: "memory");
    __builtin_amdgcn_s_barrier();

    // ================= phase B: A(mf4-7), stage 2, MFMA 32 =====================
    if (kt + 1 < NT_) {
      GLA(nx, kt+1, 1); GLA(nx, kt+1, 3);          // A-late (rows 64-127,192-255)
    }
    {
      s16x8 af[4][2];
      #pragma unroll
      for (int f = 0; f < 4; ++f) {
        af[f][0] = *(const s16x8*)(SH + cur*32768 + aFB + (f+4)*2048 + kof0);
        af[f][1] = *(const s16x8*)(SH + cur*32768 + aFB + (f+4)*2048 + kof1);
      }
      __builtin_amdgcn_s_setprio(1);
      #pragma unroll
      for (int f = 0; f < 4; ++f)
        #pragma unroll
        for (int nf = 0; nf < 4; ++nf)
          #pragma unroll
          for (int ks = 0; ks < 2; ++ks)
            acc[f + 4][nf] = __builtin_amdgcn_mfma_f32_16x16x32_bf16(
                af[f][ks], bfr[nf][ks], acc[f + 4][nf], 0, 0, 0);
      __builtin_amdgcn_s_setprio(0);
    }
    if (kt + 1 < NT_) asm volatile("s_waitcnt vmcnt(2)" ::: "memory");
    __builtin_amdgcn_s_barrier();
  }
  #undef GLA
  #undef GLB

  // ---- epilogue phase 1: bias + elu+1 + rope, pack pairs as u32 into LDS ----
  #pragma unroll
  for (int nf = 0; nf < 4; ++nf) {
    const int lcol = wn*64 + nf*16 + (l & 15);       // 0..255 (parity == l&1)
    const int col = n0 + lcol;
    const float bias = bqk[col];
    const int cc = col & 1023;
    const float cn = ctab[cc >> 1];
    const float sn = stab[cc >> 1];
    const int lcolp2 = (lcol & ~1) * 2;              // pair byte offset in row
    #pragma unroll
    for (int mf = 0; mf < 8; ++mf) {
      #pragma unroll
      for (int j = 0; j < 4; ++j) {
        const int rloc = wm*128 + mf*16 + ((l >> 4) << 2) + j;
        float v = acc[mf][nf][j] + bias;
        v = (v > 0.f) ? (v + 1.f) : __expf(v);      // elu(v)+1
        const float vp = __shfl_xor(v, 1);          // partner column (elu'd)
        if (((l & 1) == 0) == (mf < 4)) {           // split duty: even->mf0-3
          const float e = (l & 1) ? vp : v;         // even-col value
          const float o = (l & 1) ? v : vp;         // odd-col value
          const unsigned pack = (unsigned)f2bf(cn*e - sn*o)
                              | ((unsigned)f2bf(sn*e + cn*o) << 16);
          *(unsigned*)(SH + rloc*512 + (lcolp2 ^ ((rloc & 7) << 4))) = pack;
        }
      }
    }
  }
  __syncthreads();
  // ---- epilogue phase 2: coalesced 16B stores (full rows) ----
  {
    u16* dst = (n0 < 1024) ? qrb : krb;
    const int colbase = n0 & 1023;
    #pragma unroll
    for (int it = 0; it < 16; ++it) {
      const int chunk = it*512 + t;      // 8192 chunks of 16B
      const int r = chunk >> 5;          // row 0..255
      const int c = chunk & 31;          // 16B chunk in row (8 cols)
      const s16x8 val = *(const s16x8*)(SH + r*512 + ((c ^ (r & 7)) << 4));
      *(s16x8*)(dst + (size_t)(m0 + r)*1024 + colbase + c*8) = val;
    }
  }
}

// ---------------- kernel 2: kv partials: 8d x 8e per thread, 16 n-slices ----------
__global__ __launch_bounds__(256, 4) void kvpart_kernel(
    const u16* __restrict__ krb, const u16* __restrict__ xb,
    float* __restrict__ partial, float* __restrict__ ksump)
{
  __shared__ float red[2][64][65];   // odd stride: conflict-free lane columns
  __shared__ float ksred[4][64];
  const int t = threadIdx.x;
  const int l = t & 63;
  const int nsub = t >> 6;
  const int dg = l >> 3, eg = l & 7;
  const int d0 = dg*8, e0 = eg*8;
  const int blk = blockIdx.x;
  const int bh = blk >> 4;
  const int ns = blk & 15;
  const int b = bh >> 4, h = bh & 15;

  float acc[8][8];
  #pragma unroll
  for (int i=0;i<8;++i)
    #pragma unroll
    for (int j=0;j<8;++j) acc[i][j]=0.f;
  float ksum[8];
  #pragma unroll
  for (int i=0;i<8;++i) ksum[i]=0.f;

  const size_t base = ((size_t)b*4096 + ns*256 + nsub*64) * 1024 + h*64;
  #pragma unroll 2
  for (int it = 0; it < 64; ++it) {
    const size_t roff = base + (size_t)it*1024;
    const s16x8 k8 = *(const s16x8*)(krb + roff + d0);
    const s16x8 v8 = *(const s16x8*)(xb + roff + e0);
    float kf[8], vf[8];
    #pragma unroll
    for (int i=0;i<8;++i){ kf[i]=bf2f((u16)k8[i]); vf[i]=bf2f((u16)v8[i]); }
    #pragma unroll
    for (int i=0;i<8;++i){
      ksum[i]+=kf[i];
      #pragma unroll
      for (int j=0;j<8;++j) acc[i][j] += kf[i]*vf[j];
    }
  }

  if (eg == 0) {
    #pragma unroll
    for (int i=0;i<8;++i) ksred[nsub][d0+i] = ksum[i];
  }
  if (nsub >= 2) {
    #pragma unroll
    for (int i=0;i<8;++i)
      #pragma unroll
      for (int j=0;j<8;++j) red[nsub-2][l][i*8+j] = acc[i][j];
  }
  __syncthreads();
  if (t < 64) {
    const float s4 = ksred[0][t]+ksred[1][t]+ksred[2][t]+ksred[3][t];
    ksump[((size_t)ns*64 + bh)*64 + t] = s4;
  }
  if (nsub < 2) {
    #pragma unroll
    for (int i=0;i<8;++i)
      #pragma unroll
      for (int j=0;j<8;++j) acc[i][j] += red[nsub][l][i*8+j];
  }
  __syncthreads();
  if (nsub == 1) {
    #pragma unroll
    for (int i=0;i<8;++i)
      #pragma unroll
      for (int j=0;j<8;++j) red[0][l][i*8+j] = acc[i][j];
  }
  __syncthreads();
  if (nsub == 0) {
    float* dst = partial + ((size_t)ns*64 + bh)*4096 + d0*64 + e0;
    #pragma unroll
    for (int i=0;i<8;++i) {
      f32x4 lo, hi;
      #pragma unroll
      for (int j=0;j<4;++j) { lo[j] = acc[i][j] + red[0][l][i*8+j];
                              hi[j] = acc[i][j+4] + red[0][l][i*8+j+4]; }
      *(f32x4*)(dst + i*64)     = lo;
      *(f32x4*)(dst + i*64 + 4) = hi;
    }
  }
}

// ---------------- kernel 2b: sum 16 slices, *1/n, transpose -> kvbT bf16; kmr ----
__global__ __launch_bounds__(256) void kvred_kernel(
    const float* __restrict__ partial, const float* __restrict__ ksump,
    u16* __restrict__ kvbT, float* __restrict__ kmr)
{
  __shared__ float s[4096];
  const int bh = blockIdx.x;
  const int t = threadIdx.x;
  const float inv_n = 1.f / 4096.f;
  f32x4 a0={0,0,0,0}, a1={0,0,0,0}, a2={0,0,0,0}, a3={0,0,0,0};
  #pragma unroll
  for (int sl=0; sl<16; ++sl) {
    const f32x4* p = (const f32x4*)(partial + ((size_t)sl*64 + bh)*4096 + t*16);
    a0 += p[0]; a1 += p[1]; a2 += p[2]; a3 += p[3];
  }
  ((f32x4*)s)[t*4+0]=a0; ((f32x4*)s)[t*4+1]=a1;
  ((f32x4*)s)[t*4+2]=a2; ((f32x4*)s)[t*4+3]=a3;
  if (t < 64) {
    float ks = 0.f;
    #pragma unroll
    for (int sl = 0; sl < 16; ++sl) ks += ksump[((size_t)sl*64 + bh)*64 + t];
    kmr[bh*64 + t] = ks * inv_n;
  }
  __syncthreads();
  s16x8 o0, o1;
  #pragma unroll
  for (int j=0;j<8;++j) {
    o0[j] = (short)f2bf(s[((t&3)*16 + j)*64 + (t>>2)] * inv_n);
    o1[j] = (short)f2bf(s[((t&3)*16 + 8 + j)*64 + (t>>2)] * inv_n);
  }
  *(s16x8*)(kvbT + (size_t)bh*4096 + t*16) = o0;
  *(s16x8*)(kvbT + (size_t)bh*4096 + t*16 + 8) = o1;
}

// ---------------- kernel 3: attn MFMA + fused z + z scale + fused pe conv ----------
__global__ __launch_bounds__(256) void attn_kernel(
    const u16* __restrict__ qrb, const u16* __restrict__ kvbT,
    const float* __restrict__ kmr, const u16* __restrict__ xb,
    const float* __restrict__ lw, const float* __restrict__ lb,
    float* __restrict__ out)
{
  __shared__ __align__(16) unsigned char As[16384]; // 128 rows x 128B
  __shared__ __align__(16) unsigned char Bs[8192];  // 64 rows x 128B
  __shared__ float lws[192], lbs[64];
  __shared__ float kms[64];
  __shared__ float zs[128];
  const int t = threadIdx.x, l = t & 63, w = t >> 6;
  const int m0 = blockIdx.x * 128;
  const int h = blockIdx.y, b = blockIdx.z;
  const size_t qbase = ((size_t)b*4096 + m0) * 1024 + h*64;   // row-major
  const u16* kvsrc = kvbT + ((size_t)(b*16 + h) << 12);

  #pragma unroll
  for (int i = 0; i < 4; ++i) {
    const int jc   = i*256 + t;
    const int row  = jc >> 3;                          // 0..127
    const int cole = (((jc & 7) << 4) ^ ((row & 7) << 4)) >> 1;
    const int ldsoff = (i*256 + w*64) * 16;
    __builtin_amdgcn_global_load_lds(
      (const __attribute__((address_space(1))) void*)(qrb + qbase + (size_t)row*1024 + cole),
      (__attribute__((address_space(3))) void*)(As + ldsoff), 16, 0, 0);
  }
  #pragma unroll
  for (int i = 0; i < 2; ++i) {
    const int jc   = i*256 + t;
    const int row  = jc >> 3;                          // e: 0..63
    const int cole = (((jc & 7) << 4) ^ ((row & 7) << 4)) >> 1;
    const int ldsoff = (i*256 + w*64) * 16;
    __builtin_amdgcn_global_load_lds(
      (const __attribute__((address_space(1))) void*)(kvsrc + (size_t)row*64 + cole),
      (__attribute__((address_space(3))) void*)(Bs + ldsoff), 16, 0, 0);
  }
  if (t < 192) lws[t] = lw[h*192 + t];
  if (t >= 192)  lbs[t-192] = lb[h*64 + (t-192)];
  if (t < 64) kms[t] = kmr[(b*16 + h)*64 + t];
  __syncthreads();

  // fused z: row r = t>>1, d-half = t&1; q from swizzled As
  {
    const int r = t >> 1, half = t & 1;
    const int swz = (r & 7) << 4;
    float zp = 0.f;
    #pragma unroll
    for (int c = 0; c < 4; ++c) {
      const int kb = half*64 + c*16;
      const s16x8 qv = *(const s16x8*)(As + r*128 + (kb ^ swz));
      #pragma unroll
      for (int j = 0; j < 8; ++j) zp += bf2f((u16)qv[j]) * kms[half*32 + c*8 + j];
    }
    zp += __shfl_xor(zp, 1);
    if (!half) zs[r] = 1.f / (zp + 1e-6f);
  }

  f32x4 acc[2][4];
  #pragma unroll
  for (int a = 0; a < 2; ++a)
    #pragma unroll
    for (int c = 0; c < 4; ++c) acc[a][c] = (f32x4){0.f,0.f,0.f,0.f};

  #pragma unroll
  for (int ks = 0; ks < 2; ++ks) {
    const int kbyte = ks*64 + ((l >> 4) << 4);
    s16x8 af[2], bf[4];
    #pragma unroll
    for (int mi = 0; mi < 2; ++mi) {
      const int r = w*32 + mi*16 + (l & 15);
      af[mi] = *(const s16x8*)(As + r*128 + (kbyte ^ ((r & 7) << 4)));
    }
    #pragma unroll
    for (int ni = 0; ni < 4; ++ni) {
      const int r = ni*16 + (l & 15);
      bf[ni] = *(const s16x8*)(Bs + r*128 + (kbyte ^ ((r & 7) << 4)));
    }
    #pragma unroll
    for (int mi = 0; mi < 2; ++mi)
      #pragma unroll
      for (int ni = 0; ni < 4; ++ni)
        acc[mi][ni] = __builtin_amdgcn_mfma_f32_16x16x32_bf16(af[mi], bf[ni], acc[mi][ni], 0, 0, 0);
  }
  __syncthreads();   // zs ready for epilogue

  // epilogue: out = acc * z[row] + pe(xb)
  #pragma unroll
  for (int mi = 0; mi < 2; ++mi) {
    #pragma unroll
    for (int j = 0; j < 4; ++j) {
      const int rowm = m0 + w*32 + mi*16 + ((l >> 4) << 2) + j;
      const float zr = zs[rowm - m0];
      const size_t rbase = ((size_t)b*4096 + rowm)*1024;
      #pragma unroll
      for (int ni = 0; ni < 4; ++ni) {
        const int cl = ni*16 + (l & 15);       // in-head channel 0..63
        const int c = h*64 + cl;
        float pe = lbs[cl] + bf2f(xb[rbase + c])*lws[cl*3+1];
        if (rowm > 0)    pe += bf2f(xb[rbase - 1024 + c])*lws[cl*3];
        if (rowm < 4095) pe += bf2f(xb[rbase + 1024 + c])*lws[cl*3+2];
        out[rbase + c] = acc[mi][ni][j]*zr + pe;
      }
    }
  }
}

extern "C" void kernel_launch(void* const* d_in, const int* in_sizes, int n_in,
                              void* d_out, int out_size, void* d_ws, size_t ws_size,
                              hipStream_t stream) {
  const float* x   = (const float*)d_in[0];
  const float* Wqk = (const float*)d_in[1];
  const float* bqk = (const float*)d_in[2];
  const float* lw  = (const float*)d_in[3];
  const float* lb  = (const float*)d_in[4];
  float* out = (float*)d_out;

  char* ws = (char*)d_ws;
  u16* xb    = (u16*)(ws);                       // 33.55 MB  x bf16
  u16* qrb   = (u16*)(ws + 33554432ull);         // 33.55 MB  q_rope bf16 (row-major)
  u16* krb   = (u16*)(ws + 67108864ull);         // 33.55 MB  k_rope bf16 (row-major)
  u16* wb    = (u16*)(ws + 100663296ull);        //  4.19 MB  W bf16
  float* kmr = (float*)(ws + 104857600ull);      // 16 KB     fp32
  float* ctab= (float*)(ws + 104874368ull);      //  2 KB
  float* stab= (float*)(ws + 104876416ull);      //  2 KB
  u16* kvbT  = (u16*)(ws + 104878464ull);        // 0.5 MB    kv^T bf16
  // kv partials (16.7 MB) + ksump (256 KB) live in d_out scratch;
  // attn overwrites all of out afterwards (stream-ordered).
  float* partial = out;
  float* ksump   = out + 4194304;

  hipLaunchKernelGGL(trig_kernel, dim3(1), dim3(512), 0, stream, ctab, stab);
  hipLaunchKernelGGL(cast_kernel, dim3(2048), dim3(256), 0, stream, x, Wqk, xb, wb);
  hipLaunchKernelGGL(gemm_kernel, dim3(64, 8), dim3(512), 0, stream, xb, wb, bqk, ctab, stab, qrb, krb);
  hipLaunchKernelGGL(kvpart_kernel, dim3(1024), dim3(256), 0, stream, krb, xb, partial, ksump);
  hipLaunchKernelGGL(kvred_kernel, dim3(64), dim3(256), 0, stream, partial, ksump, kvbT, kmr);
  hipLaunchKernelGGL(attn_kernel, dim3(32, 16, 4), dim3(256), 0, stream, qrb, kvbT, kmr, xb, lw, lb, out);
}

// Round 17
// 184.670 us; speedup vs baseline: 1.7443x; 1.1102x over previous
//
#include <hip/hip_runtime.h>
#include <hip/hip_bf16.h>
#include <math.h>

typedef unsigned short u16;
typedef __attribute__((ext_vector_type(8))) short s16x8;
typedef __attribute__((ext_vector_type(4))) float f32x4;

#define B_ 4
#define N_ 4096
#define C_ 1024
#define M_ (B_*N_)
#define NT_ 16   // K / 64

__device__ __forceinline__ u16 f2bf(float f) {
  unsigned u = __builtin_bit_cast(unsigned, f);
  u = u + 0x7fffu + ((u >> 16) & 1u);
  return (u16)(u >> 16);
}
__device__ __forceinline__ float bf2f(u16 h) {
  unsigned u = ((unsigned)h) << 16;
  return __builtin_bit_cast(float, u);
}

// ---------------- kernel T: one-time rope trig table (512 pairs, 2 blocks) ------
__global__ void trig_kernel(float* __restrict__ ctab, float* __restrict__ stab) {
  const int i = blockIdx.x*256 + threadIdx.x;   // 0..511
  const float theta = powf(10000.f, -(float)i * (1.f/512.f));
  ctab[i] = cosf(theta);
  stab[i] = sinf(theta);
}

// ---------------- kernel 0: fp32 -> bf16 precast of x and W ----------------
__global__ __launch_bounds__(256) void cast_kernel(
    const float* __restrict__ x, const float* __restrict__ w,
    u16* __restrict__ xb, u16* __restrict__ wb)
{
  const int NX4 = M_*C_/4;     // 4194304
  const int NW4 = 2048*C_/4;   // 524288
  int tid = blockIdx.x*256 + threadIdx.x;
  int stride = gridDim.x*256;
  for (int i = tid; i < NX4; i += stride) {
    f32x4 v = ((const f32x4*)x)[i];
    ushort4 o;
    o.x = f2bf(v[0]); o.y = f2bf(v[1]); o.z = f2bf(v[2]); o.w = f2bf(v[3]);
    ((ushort4*)xb)[i] = o;
  }
  for (int i = tid; i < NW4; i += stride) {
    f32x4 v = ((const f32x4*)w)[i];
    ushort4 o;
    o.x = f2bf(v[0]); o.y = f2bf(v[1]); o.z = f2bf(v[2]); o.w = f2bf(v[3]);
    ((ushort4*)wb)[i] = o;
  }
}

// ---------------- kernel 1: qk GEMM + bias + elu+1 + ROPE -> q_rope,k_rope ----
// FROZEN (R16): 2-phase/2-barrier counted-vmcnt schedule, unrolled kt, precomputed
// lane offsets, coalesced LDS-transposed epilogue. 94-96us, 731 TF.
__global__ __launch_bounds__(512, 2) void gemm_kernel(
    const u16* __restrict__ xb, const u16* __restrict__ wb,
    const float* __restrict__ bqk,
    const float* __restrict__ ctab, const float* __restrict__ stab,
    u16* __restrict__ qrb, u16* __restrict__ krb)
{
  __shared__ __align__(16) unsigned char SH[131072];   // A: [0,64K) 2 bufs; B: [64K,128K)
  const int t = threadIdx.x;             // 0..511
  const int l = t & 63;
  const int w = t >> 6;                  // 0..7
  const int wm = w >> 2, wn = w & 3;     // 2M x 4N
  const int m0 = blockIdx.x * 256;
  const int n0 = blockIdx.y * 256;

  f32x4 acc[8][4];
  #pragma unroll
  for (int a = 0; a < 8; ++a)
    #pragma unroll
    for (int b = 0; b < 4; ++b) acc[a][b] = (f32x4){0.f,0.f,0.f,0.f};

  const int s_cole = ((t & 7) ^ ((t >> 3) & 7)) << 3;      // pre-swizzled col
  const u16* aS = xb + (size_t)(m0 + (t >> 3)) * 1024 + s_cole;
  const u16* bS = wb + (size_t)(n0 + (t >> 3)) * 1024 + s_cole;
  const int ldsW = w*1024;                                  // w*64*16 bytes

  #define GLA(buf, kt, i_)                                                     \
    __builtin_amdgcn_global_load_lds(                                          \
      (const __attribute__((address_space(1))) void*)(aS + (i_)*65536 + (kt)*64), \
      (__attribute__((address_space(3))) void*)(SH + (buf)*32768 + (i_)*8192 + ldsW), 16, 0, 0)
  #define GLB(buf, kt, i_)                                                     \
    __builtin_amdgcn_global_load_lds(                                          \
      (const __attribute__((address_space(1))) void*)(bS + (i_)*65536 + (kt)*64), \
      (__attribute__((address_space(3))) void*)(SH + 65536 + (buf)*32768 + (i_)*8192 + ldsW), 16, 0, 0)

  const int swzl = (l & 7) << 4;
  const int kof0 = (((l >> 4) << 4)) ^ swzl;
  const int kof1 = (64 + ((l >> 4) << 4)) ^ swzl;
  const int aFB = wm*16384 + (l & 15)*128;   // + cur*32768 + mf*2048 + kof
  const int bFB = wn*8192  + (l & 15)*128;   // + 65536 + cur*32768 + nf*2048 + kof

  GLB(0,0,0); GLB(0,0,1); GLB(0,0,2); GLB(0,0,3);
  GLA(0,0,0); GLA(0,0,2);
  GLA(0,0,1); GLA(0,0,3);
  asm volatile("s_waitcnt vmcnt(2)" ::: "memory");
  __builtin_amdgcn_s_barrier();

  #pragma unroll
  for (int kt = 0; kt < NT_; ++kt) {
    const int cur = kt & 1;
    const int nx = cur ^ 1;

    // ================= phase A: B + A(mf0-3), stage 6, MFMA 32 =================
    if (kt + 1 < NT_) {
      GLB(nx, kt+1, 0); GLB(nx, kt+1, 1); GLB(nx, kt+1, 2); GLB(nx, kt+1, 3);
      GLA(nx, kt+1, 0); GLA(nx, kt+1, 2);          // A-early (rows 0-63,128-191)
    }
    s16x8 bfr[4][2];
    #pragma unroll
    for (int nf = 0; nf < 4; ++nf) {
      bfr[nf][0] = *(const s16x8*)(SH + 65536 + cur*32768 + bFB + nf*2048 + kof0);
      bfr[nf][1] = *(const s16x8*)(SH + 65536 + cur*32768 + bFB + nf*2048 + kof1);
    }
    {
      s16x8 af[4][2];
      #pragma unroll
      for (int f = 0; f < 4; ++f) {
        af[f][0] = *(const s16x8*)(SH + cur*32768 + aFB + f*2048 + kof0);
        af[f][1] = *(const s16x8*)(SH + cur*32768 + aFB + f*2048 + kof1);
      }
      __builtin_amdgcn_s_setprio(1);
      #pragma unroll
      for (int f = 0; f < 4; ++f)
        #pragma unroll
        for (int nf = 0; nf < 4; ++nf)
          #pragma unroll
          for (int ks = 0; ks < 2; ++ks)
            acc[f][nf] = __builtin_amdgcn_mfma_f32_16x16x32_bf16(
                af[f][ks], bfr[nf][ks], acc[f][nf], 0, 0, 0);
      __builtin_amdgcn_s_setprio(0);
    }
    if (kt + 1 < NT_) asm volatile("s_waitcnt vmcnt(6)" ::: "memory");
    else              asm volatile("s_waitcnt vmcnt(0)" ::: "memory");
    __builtin_amdgcn_s_barrier();

    // ================= phase B: A(mf4-7), stage 2, MFMA 32 =====================
    if (kt + 1 < NT_) {
      GLA(nx, kt+1, 1); GLA(nx, kt+1, 3);          // A-late (rows 64-127,192-255)
    }
    {
      s16x8 af[4][2];
      #pragma unroll
      for (int f = 0; f < 4; ++f) {
        af[f][0] = *(const s16x8*)(SH + cur*32768 + aFB + (f+4)*2048 + kof0);
        af[f][1] = *(const s16x8*)(SH + cur*32768 + aFB + (f+4)*2048 + kof1);
      }
      __builtin_amdgcn_s_setprio(1);
      #pragma unroll
      for (int f = 0; f < 4; ++f)
        #pragma unroll
        for (int nf = 0; nf < 4; ++nf)
          #pragma unroll
          for (int ks = 0; ks < 2; ++ks)
            acc[f + 4][nf] = __builtin_amdgcn_mfma_f32_16x16x32_bf16(
                af[f][ks], bfr[nf][ks], acc[f + 4][nf], 0, 0, 0);
      __builtin_amdgcn_s_setprio(0);
    }
    if (kt + 1 < NT_) asm volatile("s_waitcnt vmcnt(2)" ::: "memory");
    __builtin_amdgcn_s_barrier();
  }
  #undef GLA
  #undef GLB

  // ---- epilogue phase 1: bias + elu+1 + rope, pack pairs as u32 into LDS ----
  #pragma unroll
  for (int nf = 0; nf < 4; ++nf) {
    const int lcol = wn*64 + nf*16 + (l & 15);       // 0..255 (parity == l&1)
    const int col = n0 + lcol;
    const float bias = bqk[col];
    const int cc = col & 1023;
    const float cn = ctab[cc >> 1];
    const float sn = stab[cc >> 1];
    const int lcolp2 = (lcol & ~1) * 2;              // pair byte offset in row
    #pragma unroll
    for (int mf = 0; mf < 8; ++mf) {
      #pragma unroll
      for (int j = 0; j < 4; ++j) {
        const int rloc = wm*128 + mf*16 + ((l >> 4) << 2) + j;
        float v = acc[mf][nf][j] + bias;
        v = (v > 0.f) ? (v + 1.f) : __expf(v);      // elu(v)+1
        const float vp = __shfl_xor(v, 1);          // partner column (elu'd)
        if (((l & 1) == 0) == (mf < 4)) {           // split duty: even->mf0-3
          const float e = (l & 1) ? vp : v;         // even-col value
          const float o = (l & 1) ? v : vp;         // odd-col value
          const unsigned pack = (unsigned)f2bf(cn*e - sn*o)
                              | ((unsigned)f2bf(sn*e + cn*o) << 16);
          *(unsigned*)(SH + rloc*512 + (lcolp2 ^ ((rloc & 7) << 4))) = pack;
        }
      }
    }
  }
  __syncthreads();
  // ---- epilogue phase 2: coalesced 16B stores (full rows) ----
  {
    u16* dst = (n0 < 1024) ? qrb : krb;
    const int colbase = n0 & 1023;
    #pragma unroll
    for (int it = 0; it < 16; ++it) {
      const int chunk = it*512 + t;      // 8192 chunks of 16B
      const int r = chunk >> 5;          // row 0..255
      const int c = chunk & 31;          // 16B chunk in row (8 cols)
      const s16x8 val = *(const s16x8*)(SH + r*512 + ((c ^ (r & 7)) << 4));
      *(s16x8*)(dst + (size_t)(m0 + r)*1024 + colbase + c*8) = val;
    }
  }
}

// ---------------- kernel 2: kv partials: 8d x 8e per thread, 16 n-slices ----------
__global__ __launch_bounds__(256, 4) void kvpart_kernel(
    const u16* __restrict__ krb, const u16* __restrict__ xb,
    float* __restrict__ partial, float* __restrict__ ksump)
{
  __shared__ float red[2][64][65];   // odd stride: conflict-free lane columns
  __shared__ float ksred[4][64];
  const int t = threadIdx.x;
  const int l = t & 63;
  const int nsub = t >> 6;
  const int dg = l >> 3, eg = l & 7;
  const int d0 = dg*8, e0 = eg*8;
  const int blk = blockIdx.x;
  const int bh = blk >> 4;
  const int ns = blk & 15;
  const int b = bh >> 4, h = bh & 15;

  float acc[8][8];
  #pragma unroll
  for (int i=0;i<8;++i)
    #pragma unroll
    for (int j=0;j<8;++j) acc[i][j]=0.f;
  float ksum[8];
  #pragma unroll
  for (int i=0;i<8;++i) ksum[i]=0.f;

  const size_t base = ((size_t)b*4096 + ns*256 + nsub*64) * 1024 + h*64;
  #pragma unroll 2
  for (int it = 0; it < 64; ++it) {
    const size_t roff = base + (size_t)it*1024;
    const s16x8 k8 = *(const s16x8*)(krb + roff + d0);
    const s16x8 v8 = *(const s16x8*)(xb + roff + e0);
    float kf[8], vf[8];
    #pragma unroll
    for (int i=0;i<8;++i){ kf[i]=bf2f((u16)k8[i]); vf[i]=bf2f((u16)v8[i]); }
    #pragma unroll
    for (int i=0;i<8;++i){
      ksum[i]+=kf[i];
      #pragma unroll
      for (int j=0;j<8;++j) acc[i][j] += kf[i]*vf[j];
    }
  }

  if (eg == 0) {
    #pragma unroll
    for (int i=0;i<8;++i) ksred[nsub][d0+i] = ksum[i];
  }
  if (nsub >= 2) {
    #pragma unroll
    for (int i=0;i<8;++i)
      #pragma unroll
      for (int j=0;j<8;++j) red[nsub-2][l][i*8+j] = acc[i][j];
  }
  __syncthreads();
  if (t < 64) {
    const float s4 = ksred[0][t]+ksred[1][t]+ksred[2][t]+ksred[3][t];
    ksump[((size_t)ns*64 + bh)*64 + t] = s4;
  }
  if (nsub < 2) {
    #pragma unroll
    for (int i=0;i<8;++i)
      #pragma unroll
      for (int j=0;j<8;++j) acc[i][j] += red[nsub][l][i*8+j];
  }
  __syncthreads();
  if (nsub == 1) {
    #pragma unroll
    for (int i=0;i<8;++i)
      #pragma unroll
      for (int j=0;j<8;++j) red[0][l][i*8+j] = acc[i][j];
  }
  __syncthreads();
  if (nsub == 0) {
    float* dst = partial + ((size_t)ns*64 + bh)*4096 + d0*64 + e0;
    #pragma unroll
    for (int i=0;i<8;++i) {
      f32x4 lo, hi;
      #pragma unroll
      for (int j=0;j<4;++j) { lo[j] = acc[i][j] + red[0][l][i*8+j];
                              hi[j] = acc[i][j+4] + red[0][l][i*8+j+4]; }
      *(f32x4*)(dst + i*64)     = lo;
      *(f32x4*)(dst + i*64 + 4) = hi;
    }
  }
}

// ---------------- kernel 2b: sum 16 slices, *1/n, transpose -> kvbT bf16; kmr ----
__global__ __launch_bounds__(256) void kvred_kernel(
    const float* __restrict__ partial, const float* __restrict__ ksump,
    u16* __restrict__ kvbT, float* __restrict__ kmr)
{
  __shared__ float s[4096];
  const int bh = blockIdx.x;
  const int t = threadIdx.x;
  const float inv_n = 1.f / 4096.f;
  f32x4 a0={0,0,0,0}, a1={0,0,0,0}, a2={0,0,0,0}, a3={0,0,0,0};
  #pragma unroll
  for (int sl=0; sl<16; ++sl) {
    const f32x4* p = (const f32x4*)(partial + ((size_t)sl*64 + bh)*4096 + t*16);
    a0 += p[0]; a1 += p[1]; a2 += p[2]; a3 += p[3];
  }
  ((f32x4*)s)[t*4+0]=a0; ((f32x4*)s)[t*4+1]=a1;
  ((f32x4*)s)[t*4+2]=a2; ((f32x4*)s)[t*4+3]=a3;
  if (t < 64) {
    float ks = 0.f;
    #pragma unroll
    for (int sl = 0; sl < 16; ++sl) ks += ksump[((size_t)sl*64 + bh)*64 + t];
    kmr[bh*64 + t] = ks * inv_n;
  }
  __syncthreads();
  s16x8 o0, o1;
  #pragma unroll
  for (int j=0;j<8;++j) {
    o0[j] = (short)f2bf(s[((t&3)*16 + j)*64 + (t>>2)] * inv_n);
    o1[j] = (short)f2bf(s[((t&3)*16 + 8 + j)*64 + (t>>2)] * inv_n);
  }
  *(s16x8*)(kvbT + (size_t)bh*4096 + t*16) = o0;
  *(s16x8*)(kvbT + (size_t)bh*4096 + t*16 + 8) = o1;
}

// ---------------- kernel 3: attn MFMA + fused z + z scale + fused pe conv ----------
// NEW: pe x-tile staged in LDS (rows m0-1..m0+128 x 64ch, 144B stride) -- removes
// 96 scalar 2B global loads per thread from the epilogue.
__global__ __launch_bounds__(256) void attn_kernel(
    const u16* __restrict__ qrb, const u16* __restrict__ kvbT,
    const float* __restrict__ kmr, const u16* __restrict__ xb,
    const float* __restrict__ lw, const float* __restrict__ lb,
    float* __restrict__ out)
{
  __shared__ __align__(16) unsigned char As[16384]; // 128 rows x 128B
  __shared__ __align__(16) unsigned char Bs[8192];  // 64 rows x 128B
  __shared__ __align__(16) u16 pes[130*72];         // pe tile, 144B row stride
  __shared__ float lws[192], lbs[64];
  __shared__ float kms[64];
  __shared__ float zs[128];
  const int t = threadIdx.x, l = t & 63, w = t >> 6;
  const int m0 = blockIdx.x * 128;
  const int h = blockIdx.y, b = blockIdx.z;
  const size_t qbase = ((size_t)b*4096 + m0) * 1024 + h*64;   // row-major
  const u16* kvsrc = kvbT + ((size_t)(b*16 + h) << 12);

  #pragma unroll
  for (int i = 0; i < 4; ++i) {
    const int jc   = i*256 + t;
    const int row  = jc >> 3;                          // 0..127
    const int cole = (((jc & 7) << 4) ^ ((row & 7) << 4)) >> 1;
    const int ldsoff = (i*256 + w*64) * 16;
    __builtin_amdgcn_global_load_lds(
      (const __attribute__((address_space(1))) void*)(qrb + qbase + (size_t)row*1024 + cole),
      (__attribute__((address_space(3))) void*)(As + ldsoff), 16, 0, 0);
  }
  #pragma unroll
  for (int i = 0; i < 2; ++i) {
    const int jc   = i*256 + t;
    const int row  = jc >> 3;                          // e: 0..63
    const int cole = (((jc & 7) << 4) ^ ((row & 7) << 4)) >> 1;
    const int ldsoff = (i*256 + w*64) * 16;
    __builtin_amdgcn_global_load_lds(
      (const __attribute__((address_space(1))) void*)(kvsrc + (size_t)row*64 + cole),
      (__attribute__((address_space(3))) void*)(Bs + ldsoff), 16, 0, 0);
  }
  // pe tile: 1040 chunks of 16B (130 rows x 8 chunks); zero-fill out-of-range rows
  #pragma unroll
  for (int it = 0; it < 5; ++it) {
    const int chunk = it*256 + t;
    if (chunk < 1040) {
      const int prow = chunk >> 3;             // 0..129
      const int sub = chunk & 7;
      const int gr = m0 - 1 + prow;            // global row in batch
      s16x8 v = (s16x8){0,0,0,0,0,0,0,0};
      if (gr >= 0 && gr <= 4095)
        v = *(const s16x8*)(xb + ((size_t)b*4096 + gr)*1024 + h*64 + sub*8);
      *(s16x8*)(pes + prow*72 + sub*8) = v;
    }
  }
  if (t < 192) lws[t] = lw[h*192 + t];
  if (t >= 192)  lbs[t-192] = lb[h*64 + (t-192)];
  if (t < 64) kms[t] = kmr[(b*16 + h)*64 + t];
  __syncthreads();

  // fused z: row r = t>>1, d-half = t&1; q from swizzled As
  {
    const int r = t >> 1, half = t & 1;
    const int swz = (r & 7) << 4;
    float zp = 0.f;
    #pragma unroll
    for (int c = 0; c < 4; ++c) {
      const int kb = half*64 + c*16;
      const s16x8 qv = *(const s16x8*)(As + r*128 + (kb ^ swz));
      #pragma unroll
      for (int j = 0; j < 8; ++j) zp += bf2f((u16)qv[j]) * kms[half*32 + c*8 + j];
    }
    zp += __shfl_xor(zp, 1);
    if (!half) zs[r] = 1.f / (zp + 1e-6f);
  }

  f32x4 acc[2][4];
  #pragma unroll
  for (int a = 0; a < 2; ++a)
    #pragma unroll
    for (int c = 0; c < 4; ++c) acc[a][c] = (f32x4){0.f,0.f,0.f,0.f};

  #pragma unroll
  for (int ks = 0; ks < 2; ++ks) {
    const int kbyte = ks*64 + ((l >> 4) << 4);
    s16x8 af[2], bf[4];
    #pragma unroll
    for (int mi = 0; mi < 2; ++mi) {
      const int r = w*32 + mi*16 + (l & 15);
      af[mi] = *(const s16x8*)(As + r*128 + (kbyte ^ ((r & 7) << 4)));
    }
    #pragma unroll
    for (int ni = 0; ni < 4; ++ni) {
      const int r = ni*16 + (l & 15);
      bf[ni] = *(const s16x8*)(Bs + r*128 + (kbyte ^ ((r & 7) << 4)));
    }
    #pragma unroll
    for (int mi = 0; mi < 2; ++mi)
      #pragma unroll
      for (int ni = 0; ni < 4; ++ni)
        acc[mi][ni] = __builtin_amdgcn_mfma_f32_16x16x32_bf16(af[mi], bf[ni], acc[mi][ni], 0, 0, 0);
  }
  __syncthreads();   // zs + pes ready for epilogue

  // epilogue: out = acc * z[row] + pe(pes)
  #pragma unroll
  for (int mi = 0; mi < 2; ++mi) {
    #pragma unroll
    for (int j = 0; j < 4; ++j) {
      const int rowm = m0 + w*32 + mi*16 + ((l >> 4) << 2) + j;
      const int prow = rowm - m0 + 1;          // 1..128 in pes
      const float zr = zs[rowm - m0];
      const size_t rbase = ((size_t)b*4096 + rowm)*1024;
      #pragma unroll
      for (int ni = 0; ni < 4; ++ni) {
        const int cl = ni*16 + (l & 15);       // in-head channel 0..63
        const int c = h*64 + cl;
        const float pe = lbs[cl]
                       + bf2f(pes[(prow-1)*72 + cl])*lws[cl*3]
                       + bf2f(pes[prow*72     + cl])*lws[cl*3+1]
                       + bf2f(pes[(prow+1)*72 + cl])*lws[cl*3+2];
        out[rbase + c] = acc[mi][ni][j]*zr + pe;
      }
    }
  }
}

extern "C" void kernel_launch(void* const* d_in, const int* in_sizes, int n_in,
                              void* d_out, int out_size, void* d_ws, size_t ws_size,
                              hipStream_t stream) {
  const float* x   = (const float*)d_in[0];
  const float* Wqk = (const float*)d_in[1];
  const float* bqk = (const float*)d_in[2];
  const float* lw  = (const float*)d_in[3];
  const float* lb  = (const float*)d_in[4];
  float* out = (float*)d_out;

  char* ws = (char*)d_ws;
  u16* xb    = (u16*)(ws);                       // 33.55 MB  x bf16
  u16* qrb   = (u16*)(ws + 33554432ull);         // 33.55 MB  q_rope bf16 (row-major)
  u16* krb   = (u16*)(ws + 67108864ull);         // 33.55 MB  k_rope bf16 (row-major)
  u16* wb    = (u16*)(ws + 100663296ull);        //  4.19 MB  W bf16
  float* kmr = (float*)(ws + 104857600ull);      // 16 KB     fp32
  float* ctab= (float*)(ws + 104874368ull);      //  2 KB
  float* stab= (float*)(ws + 104876416ull);      //  2 KB
  u16* kvbT  = (u16*)(ws + 104878464ull);        // 0.5 MB    kv^T bf16
  // kv partials (16.7 MB) + ksump (256 KB) live in d_out scratch;
  // attn overwrites all of out afterwards (stream-ordered).
  float* partial = out;
  float* ksump   = out + 4194304;

  hipLaunchKernelGGL(trig_kernel, dim3(2), dim3(256), 0, stream, ctab, stab);
  hipLaunchKernelGGL(cast_kernel, dim3(2048), dim3(256), 0, stream, x, Wqk, xb, wb);
  hipLaunchKernelGGL(gemm_kernel, dim3(64, 8), dim3(512), 0, stream, xb, wb, bqk, ctab, stab, qrb, krb);
  hipLaunchKernelGGL(kvpart_kernel, dim3(1024), dim3(256), 0, stream, krb, xb, partial, ksump);
  hipLaunchKernelGGL(kvred_kernel, dim3(64), dim3(256), 0, stream, partial, ksump, kvbT, kmr);
  hipLaunchKernelGGL(attn_kernel, dim3(32, 16, 4), dim3(256), 0, stream, qrb, kvbT, kmr, xb, lw, lb, out);
}

// Round 18
// 179.992 us; speedup vs baseline: 1.7897x; 1.0260x over previous
//
#include <hip/hip_runtime.h>
#include <hip/hip_bf16.h>
#include <math.h>

typedef unsigned short u16;
typedef __attribute__((ext_vector_type(8))) short s16x8;
typedef __attribute__((ext_vector_type(4))) float f32x4;

#define B_ 4
#define N_ 4096
#define C_ 1024
#define M_ (B_*N_)
#define NT_ 16   // K / 64

__device__ __forceinline__ u16 f2bf(float f) {
  unsigned u = __builtin_bit_cast(unsigned, f);
  u = u + 0x7fffu + ((u >> 16) & 1u);
  return (u16)(u >> 16);
}
__device__ __forceinline__ float bf2f(u16 h) {
  unsigned u = ((unsigned)h) << 16;
  return __builtin_bit_cast(float, u);
}

// ---------------- kernel 0: fp32 -> bf16 precast of x and W + rope trig tables ----
// blocks 0..2047: cast; blocks 2048..2049: trig tables (launch fused, saves a
// kernel-launch bubble; branch is block-uniform).
__global__ __launch_bounds__(256) void cast_kernel(
    const float* __restrict__ x, const float* __restrict__ w,
    u16* __restrict__ xb, u16* __restrict__ wb,
    float* __restrict__ ctab, float* __restrict__ stab)
{
  if (blockIdx.x >= 2048) {
    const int i = (blockIdx.x - 2048)*256 + threadIdx.x;   // 0..511
    const float theta = powf(10000.f, -(float)i * (1.f/512.f));
    ctab[i] = cosf(theta);
    stab[i] = sinf(theta);
    return;
  }
  const int NX4 = M_*C_/4;     // 4194304
  const int NW4 = 2048*C_/4;   // 524288
  int tid = blockIdx.x*256 + threadIdx.x;
  int stride = 2048*256;
  for (int i = tid; i < NX4; i += stride) {
    f32x4 v = ((const f32x4*)x)[i];
    ushort4 o;
    o.x = f2bf(v[0]); o.y = f2bf(v[1]); o.z = f2bf(v[2]); o.w = f2bf(v[3]);
    ((ushort4*)xb)[i] = o;
  }
  for (int i = tid; i < NW4; i += stride) {
    f32x4 v = ((const f32x4*)w)[i];
    ushort4 o;
    o.x = f2bf(v[0]); o.y = f2bf(v[1]); o.z = f2bf(v[2]); o.w = f2bf(v[3]);
    ((ushort4*)wb)[i] = o;
  }
}

// ---------------- kernel 1: qk GEMM + bias + elu+1 + ROPE -> q_rope,k_rope ----
// FROZEN (R16): 2-phase/2-barrier counted-vmcnt schedule, unrolled kt, precomputed
// lane offsets, coalesced LDS-transposed epilogue. 94us, 731 TF for this shape.
__global__ __launch_bounds__(512, 2) void gemm_kernel(
    const u16* __restrict__ xb, const u16* __restrict__ wb,
    const float* __restrict__ bqk,
    const float* __restrict__ ctab, const float* __restrict__ stab,
    u16* __restrict__ qrb, u16* __restrict__ krb)
{
  __shared__ __align__(16) unsigned char SH[131072];   // A: [0,64K) 2 bufs; B: [64K,128K)
  const int t = threadIdx.x;             // 0..511
  const int l = t & 63;
  const int w = t >> 6;                  // 0..7
  const int wm = w >> 2, wn = w & 3;     // 2M x 4N
  const int m0 = blockIdx.x * 256;
  const int n0 = blockIdx.y * 256;

  f32x4 acc[8][4];
  #pragma unroll
  for (int a = 0; a < 8; ++a)
    #pragma unroll
    for (int b = 0; b < 4; ++b) acc[a][b] = (f32x4){0.f,0.f,0.f,0.f};

  const int s_cole = ((t & 7) ^ ((t >> 3) & 7)) << 3;      // pre-swizzled col
  const u16* aS = xb + (size_t)(m0 + (t >> 3)) * 1024 + s_cole;
  const u16* bS = wb + (size_t)(n0 + (t >> 3)) * 1024 + s_cole;
  const int ldsW = w*1024;                                  // w*64*16 bytes

  #define GLA(buf, kt, i_)                                                     \
    __builtin_amdgcn_global_load_lds(                                          \
      (const __attribute__((address_space(1))) void*)(aS + (i_)*65536 + (kt)*64), \
      (__attribute__((address_space(3))) void*)(SH + (buf)*32768 + (i_)*8192 + ldsW), 16, 0, 0)
  #define GLB(buf, kt, i_)                                                     \
    __builtin_amdgcn_global_load_lds(                                          \
      (const __attribute__((address_space(1))) void*)(bS + (i_)*65536 + (kt)*64), \
      (__attribute__((address_space(3))) void*)(SH + 65536 + (buf)*32768 + (i_)*8192 + ldsW), 16, 0, 0)

  const int swzl = (l & 7) << 4;
  const int kof0 = (((l >> 4) << 4)) ^ swzl;
  const int kof1 = (64 + ((l >> 4) << 4)) ^ swzl;
  const int aFB = wm*16384 + (l & 15)*128;   // + cur*32768 + mf*2048 + kof
  const int bFB = wn*8192  + (l & 15)*128;   // + 65536 + cur*32768 + nf*2048 + kof

  GLB(0,0,0); GLB(0,0,1); GLB(0,0,2); GLB(0,0,3);
  GLA(0,0,0); GLA(0,0,2);
  GLA(0,0,1); GLA(0,0,3);
  asm volatile("s_waitcnt vmcnt(2)" ::: "memory");
  __builtin_amdgcn_s_barrier();

  #pragma unroll
  for (int kt = 0; kt < NT_; ++kt) {
    const int cur = kt & 1;
    const int nx = cur ^ 1;

    // ================= phase A: B + A(mf0-3), stage 6, MFMA 32 =================
    if (kt + 1 < NT_) {
      GLB(nx, kt+1, 0); GLB(nx, kt+1, 1); GLB(nx, kt+1, 2); GLB(nx, kt+1, 3);
      GLA(nx, kt+1, 0); GLA(nx, kt+1, 2);          // A-early (rows 0-63,128-191)
    }
    s16x8 bfr[4][2];
    #pragma unroll
    for (int nf = 0; nf < 4; ++nf) {
      bfr[nf][0] = *(const s16x8*)(SH + 65536 + cur*32768 + bFB + nf*2048 + kof0);
      bfr[nf][1] = *(const s16x8*)(SH + 65536 + cur*32768 + bFB + nf*2048 + kof1);
    }
    {
      s16x8 af[4][2];
      #pragma unroll
      for (int f = 0; f < 4; ++f) {
        af[f][0] = *(const s16x8*)(SH + cur*32768 + aFB + f*2048 + kof0);
        af[f][1] = *(const s16x8*)(SH + cur*32768 + aFB + f*2048 + kof1);
      }
      __builtin_amdgcn_s_setprio(1);
      #pragma unroll
      for (int f = 0; f < 4; ++f)
        #pragma unroll
        for (int nf = 0; nf < 4; ++nf)
          #pragma unroll
          for (int ks = 0; ks < 2; ++ks)
            acc[f][nf] = __builtin_amdgcn_mfma_f32_16x16x32_bf16(
                af[f][ks], bfr[nf][ks], acc[f][nf], 0, 0, 0);
      __builtin_amdgcn_s_setprio(0);
    }
    if (kt + 1 < NT_) asm volatile("s_waitcnt vmcnt(6)" ::: "memory");
    else              asm volatile("s_waitcnt vmcnt(0)" ::: "memory");
    __builtin_amdgcn_s_barrier();

    // ================= phase B: A(mf4-7), stage 2, MFMA 32 =====================
    if (kt + 1 < NT_) {
      GLA(nx, kt+1, 1); GLA(nx, kt+1, 3);          // A-late (rows 64-127,192-255)
    }
    {
      s16x8 af[4][2];
      #pragma unroll
      for (int f = 0; f < 4; ++f) {
        af[f][0] = *(const s16x8*)(SH + cur*32768 + aFB + (f+4)*2048 + kof0);
        af[f][1] = *(const s16x8*)(SH + cur*32768 + aFB + (f+4)*2048 + kof1);
      }
      __builtin_amdgcn_s_setprio(1);
      #pragma unroll
      for (int f = 0; f < 4; ++f)
        #pragma unroll
        for (int nf = 0; nf < 4; ++nf)
          #pragma unroll
          for (int ks = 0; ks < 2; ++ks)
            acc[f + 4][nf] = __builtin_amdgcn_mfma_f32_16x16x32_bf16(
                af[f][ks], bfr[nf][ks], acc[f + 4][nf], 0, 0, 0);
      __builtin_amdgcn_s_setprio(0);
    }
    if (kt + 1 < NT_) asm volatile("s_waitcnt vmcnt(2)" ::: "memory");
    __builtin_amdgcn_s_barrier();
  }
  #undef GLA
  #undef GLB

  // ---- epilogue phase 1: bias + elu+1 + rope, pack pairs as u32 into LDS ----
  #pragma unroll
  for (int nf = 0; nf < 4; ++nf) {
    const int lcol = wn*64 + nf*16 + (l & 15);       // 0..255 (parity == l&1)
    const int col = n0 + lcol;
    const float bias = bqk[col];
    const int cc = col & 1023;
    const float cn = ctab[cc >> 1];
    const float sn = stab[cc >> 1];
    const int lcolp2 = (lcol & ~1) * 2;              // pair byte offset in row
    #pragma unroll
    for (int mf = 0; mf < 8; ++mf) {
      #pragma unroll
      for (int j = 0; j < 4; ++j) {
        const int rloc = wm*128 + mf*16 + ((l >> 4) << 2) + j;
        float v = acc[mf][nf][j] + bias;
        v = (v > 0.f) ? (v + 1.f) : __expf(v);      // elu(v)+1
        const float vp = __shfl_xor(v, 1);          // partner column (elu'd)
        if (((l & 1) == 0) == (mf < 4)) {           // split duty: even->mf0-3
          const float e = (l & 1) ? vp : v;         // even-col value
          const float o = (l & 1) ? v : vp;         // odd-col value
          const unsigned pack = (unsigned)f2bf(cn*e - sn*o)
                              | ((unsigned)f2bf(sn*e + cn*o) << 16);
          *(unsigned*)(SH + rloc*512 + (lcolp2 ^ ((rloc & 7) << 4))) = pack;
        }
      }
    }
  }
  __syncthreads();
  // ---- epilogue phase 2: coalesced 16B stores (full rows) ----
  {
    u16* dst = (n0 < 1024) ? qrb : krb;
    const int colbase = n0 & 1023;
    #pragma unroll
    for (int it = 0; it < 16; ++it) {
      const int chunk = it*512 + t;      // 8192 chunks of 16B
      const int r = chunk >> 5;          // row 0..255
      const int c = chunk & 31;          // 16B chunk in row (8 cols)
      const s16x8 val = *(const s16x8*)(SH + r*512 + ((c ^ (r & 7)) << 4));
      *(s16x8*)(dst + (size_t)(m0 + r)*1024 + colbase + c*8) = val;
    }
  }
}

// ---------------- kernel 2: kv partials: 8d x 8e per thread, 16 n-slices ----------
__global__ __launch_bounds__(256, 4) void kvpart_kernel(
    const u16* __restrict__ krb, const u16* __restrict__ xb,
    float* __restrict__ partial, float* __restrict__ ksump)
{
  __shared__ float red[2][64][65];   // odd stride: conflict-free lane columns
  __shared__ float ksred[4][64];
  const int t = threadIdx.x;
  const int l = t & 63;
  const int nsub = t >> 6;
  const int dg = l >> 3, eg = l & 7;
  const int d0 = dg*8, e0 = eg*8;
  const int blk = blockIdx.x;
  const int bh = blk >> 4;
  const int ns = blk & 15;
  const int b = bh >> 4, h = bh & 15;

  float acc[8][8];
  #pragma unroll
  for (int i=0;i<8;++i)
    #pragma unroll
    for (int j=0;j<8;++j) acc[i][j]=0.f;
  float ksum[8];
  #pragma unroll
  for (int i=0;i<8;++i) ksum[i]=0.f;

  const size_t base = ((size_t)b*4096 + ns*256 + nsub*64) * 1024 + h*64;
  #pragma unroll 2
  for (int it = 0; it < 64; ++it) {
    const size_t roff = base + (size_t)it*1024;
    const s16x8 k8 = *(const s16x8*)(krb + roff + d0);
    const s16x8 v8 = *(const s16x8*)(xb + roff + e0);
    float kf[8], vf[8];
    #pragma unroll
    for (int i=0;i<8;++i){ kf[i]=bf2f((u16)k8[i]); vf[i]=bf2f((u16)v8[i]); }
    #pragma unroll
    for (int i=0;i<8;++i){
      ksum[i]+=kf[i];
      #pragma unroll
      for (int j=0;j<8;++j) acc[i][j] += kf[i]*vf[j];
    }
  }

  if (eg == 0) {
    #pragma unroll
    for (int i=0;i<8;++i) ksred[nsub][d0+i] = ksum[i];
  }
  if (nsub >= 2) {
    #pragma unroll
    for (int i=0;i<8;++i)
      #pragma unroll
      for (int j=0;j<8;++j) red[nsub-2][l][i*8+j] = acc[i][j];
  }
  __syncthreads();
  if (t < 64) {
    const float s4 = ksred[0][t]+ksred[1][t]+ksred[2][t]+ksred[3][t];
    ksump[((size_t)ns*64 + bh)*64 + t] = s4;
  }
  if (nsub < 2) {
    #pragma unroll
    for (int i=0;i<8;++i)
      #pragma unroll
      for (int j=0;j<8;++j) acc[i][j] += red[nsub][l][i*8+j];
  }
  __syncthreads();
  if (nsub == 1) {
    #pragma unroll
    for (int i=0;i<8;++i)
      #pragma unroll
      for (int j=0;j<8;++j) red[0][l][i*8+j] = acc[i][j];
  }
  __syncthreads();
  if (nsub == 0) {
    float* dst = partial + ((size_t)ns*64 + bh)*4096 + d0*64 + e0;
    #pragma unroll
    for (int i=0;i<8;++i) {
      f32x4 lo, hi;
      #pragma unroll
      for (int j=0;j<4;++j) { lo[j] = acc[i][j] + red[0][l][i*8+j];
                              hi[j] = acc[i][j+4] + red[0][l][i*8+j+4]; }
      *(f32x4*)(dst + i*64)     = lo;
      *(f32x4*)(dst + i*64 + 4) = hi;
    }
  }
}

// ---------------- kernel 2b: sum 16 slices, *1/n, transpose -> kvbT bf16; kmr ----
__global__ __launch_bounds__(256) void kvred_kernel(
    const float* __restrict__ partial, const float* __restrict__ ksump,
    u16* __restrict__ kvbT, float* __restrict__ kmr)
{
  __shared__ float s[4096];
  const int bh = blockIdx.x;
  const int t = threadIdx.x;
  const float inv_n = 1.f / 4096.f;
  f32x4 a0={0,0,0,0}, a1={0,0,0,0}, a2={0,0,0,0}, a3={0,0,0,0};
  #pragma unroll
  for (int sl=0; sl<16; ++sl) {
    const f32x4* p = (const f32x4*)(partial + ((size_t)sl*64 + bh)*4096 + t*16);
    a0 += p[0]; a1 += p[1]; a2 += p[2]; a3 += p[3];
  }
  ((f32x4*)s)[t*4+0]=a0; ((f32x4*)s)[t*4+1]=a1;
  ((f32x4*)s)[t*4+2]=a2; ((f32x4*)s)[t*4+3]=a3;
  if (t < 64) {
    float ks = 0.f;
    #pragma unroll
    for (int sl = 0; sl < 16; ++sl) ks += ksump[((size_t)sl*64 + bh)*64 + t];
    kmr[bh*64 + t] = ks * inv_n;
  }
  __syncthreads();
  s16x8 o0, o1;
  #pragma unroll
  for (int j=0;j<8;++j) {
    o0[j] = (short)f2bf(s[((t&3)*16 + j)*64 + (t>>2)] * inv_n);
    o1[j] = (short)f2bf(s[((t&3)*16 + 8 + j)*64 + (t>>2)] * inv_n);
  }
  *(s16x8*)(kvbT + (size_t)bh*4096 + t*16) = o0;
  *(s16x8*)(kvbT + (size_t)bh*4096 + t*16 + 8) = o1;
}

// ---------------- kernel 3: attn MFMA + fused z + z scale + fused pe conv ----------
// pe x-tile staged in LDS (rows m0-1..m0+128 x 64ch, 144B stride).
__global__ __launch_bounds__(256) void attn_kernel(
    const u16* __restrict__ qrb, const u16* __restrict__ kvbT,
    const float* __restrict__ kmr, const u16* __restrict__ xb,
    const float* __restrict__ lw, const float* __restrict__ lb,
    float* __restrict__ out)
{
  __shared__ __align__(16) unsigned char As[16384]; // 128 rows x 128B
  __shared__ __align__(16) unsigned char Bs[8192];  // 64 rows x 128B
  __shared__ __align__(16) u16 pes[130*72];         // pe tile, 144B row stride
  __shared__ float lws[192], lbs[64];
  __shared__ float kms[64];
  __shared__ float zs[128];
  const int t = threadIdx.x, l = t & 63, w = t >> 6;
  const int m0 = blockIdx.x * 128;
  const int h = blockIdx.y, b = blockIdx.z;
  const size_t qbase = ((size_t)b*4096 + m0) * 1024 + h*64;   // row-major
  const u16* kvsrc = kvbT + ((size_t)(b*16 + h) << 12);

  #pragma unroll
  for (int i = 0; i < 4; ++i) {
    const int jc   = i*256 + t;
    const int row  = jc >> 3;                          // 0..127
    const int cole = (((jc & 7) << 4) ^ ((row & 7) << 4)) >> 1;
    const int ldsoff = (i*256 + w*64) * 16;
    __builtin_amdgcn_global_load_lds(
      (const __attribute__((address_space(1))) void*)(qrb + qbase + (size_t)row*1024 + cole),
      (__attribute__((address_space(3))) void*)(As + ldsoff), 16, 0, 0);
  }
  #pragma unroll
  for (int i = 0; i < 2; ++i) {
    const int jc   = i*256 + t;
    const int row  = jc >> 3;                          // e: 0..63
    const int cole = (((jc & 7) << 4) ^ ((row & 7) << 4)) >> 1;
    const int ldsoff = (i*256 + w*64) * 16;
    __builtin_amdgcn_global_load_lds(
      (const __attribute__((address_space(1))) void*)(kvsrc + (size_t)row*64 + cole),
      (__attribute__((address_space(3))) void*)(Bs + ldsoff), 16, 0, 0);
  }
  // pe tile: 1040 chunks of 16B (130 rows x 8 chunks); zero-fill out-of-range rows
  #pragma unroll
  for (int it = 0; it < 5; ++it) {
    const int chunk = it*256 + t;
    if (chunk < 1040) {
      const int prow = chunk >> 3;             // 0..129
      const int sub = chunk & 7;
      const int gr = m0 - 1 + prow;            // global row in batch
      s16x8 v = (s16x8){0,0,0,0,0,0,0,0};
      if (gr >= 0 && gr <= 4095)
        v = *(const s16x8*)(xb + ((size_t)b*4096 + gr)*1024 + h*64 + sub*8);
      *(s16x8*)(pes + prow*72 + sub*8) = v;
    }
  }
  if (t < 192) lws[t] = lw[h*192 + t];
  if (t >= 192)  lbs[t-192] = lb[h*64 + (t-192)];
  if (t < 64) kms[t] = kmr[(b*16 + h)*64 + t];
  __syncthreads();

  // fused z: row r = t>>1, d-half = t&1; q from swizzled As
  {
    const int r = t >> 1, half = t & 1;
    const int swz = (r & 7) << 4;
    float zp = 0.f;
    #pragma unroll
    for (int c = 0; c < 4; ++c) {
      const int kb = half*64 + c*16;
      const s16x8 qv = *(const s16x8*)(As + r*128 + (kb ^ swz));
      #pragma unroll
      for (int j = 0; j < 8; ++j) zp += bf2f((u16)qv[j]) * kms[half*32 + c*8 + j];
    }
    zp += __shfl_xor(zp, 1);
    if (!half) zs[r] = 1.f / (zp + 1e-6f);
  }

  f32x4 acc[2][4];
  #pragma unroll
  for (int a = 0; a < 2; ++a)
    #pragma unroll
    for (int c = 0; c < 4; ++c) acc[a][c] = (f32x4){0.f,0.f,0.f,0.f};

  #pragma unroll
  for (int ks = 0; ks < 2; ++ks) {
    const int kbyte = ks*64 + ((l >> 4) << 4);
    s16x8 af[2], bf[4];
    #pragma unroll
    for (int mi = 0; mi < 2; ++mi) {
      const int r = w*32 + mi*16 + (l & 15);
      af[mi] = *(const s16x8*)(As + r*128 + (kbyte ^ ((r & 7) << 4)));
    }
    #pragma unroll
    for (int ni = 0; ni < 4; ++ni) {
      const int r = ni*16 + (l & 15);
      bf[ni] = *(const s16x8*)(Bs + r*128 + (kbyte ^ ((r & 7) << 4)));
    }
    #pragma unroll
    for (int mi = 0; mi < 2; ++mi)
      #pragma unroll
      for (int ni = 0; ni < 4; ++ni)
        acc[mi][ni] = __builtin_amdgcn_mfma_f32_16x16x32_bf16(af[mi], bf[ni], acc[mi][ni], 0, 0, 0);
  }
  __syncthreads();   // zs + pes ready for epilogue

  // epilogue: out = acc * z[row] + pe(pes)
  #pragma unroll
  for (int mi = 0; mi < 2; ++mi) {
    #pragma unroll
    for (int j = 0; j < 4; ++j) {
      const int rowm = m0 + w*32 + mi*16 + ((l >> 4) << 2) + j;
      const int prow = rowm - m0 + 1;          // 1..128 in pes
      const float zr = zs[rowm - m0];
      const size_t rbase = ((size_t)b*4096 + rowm)*1024;
      #pragma unroll
      for (int ni = 0; ni < 4; ++ni) {
        const int cl = ni*16 + (l & 15);       // in-head channel 0..63
        const int c = h*64 + cl;
        const float pe = lbs[cl]
                       + bf2f(pes[(prow-1)*72 + cl])*lws[cl*3]
                       + bf2f(pes[prow*72     + cl])*lws[cl*3+1]
                       + bf2f(pes[(prow+1)*72 + cl])*lws[cl*3+2];
        out[rbase + c] = acc[mi][ni][j]*zr + pe;
      }
    }
  }
}

extern "C" void kernel_launch(void* const* d_in, const int* in_sizes, int n_in,
                              void* d_out, int out_size, void* d_ws, size_t ws_size,
                              hipStream_t stream) {
  const float* x   = (const float*)d_in[0];
  const float* Wqk = (const float*)d_in[1];
  const float* bqk = (const float*)d_in[2];
  const float* lw  = (const float*)d_in[3];
  const float* lb  = (const float*)d_in[4];
  float* out = (float*)d_out;

  char* ws = (char*)d_ws;
  u16* xb    = (u16*)(ws);                       // 33.55 MB  x bf16
  u16* qrb   = (u16*)(ws + 33554432ull);         // 33.55 MB  q_rope bf16 (row-major)
  u16* krb   = (u16*)(ws + 67108864ull);         // 33.55 MB  k_rope bf16 (row-major)
  u16* wb    = (u16*)(ws + 100663296ull);        //  4.19 MB  W bf16
  float* kmr = (float*)(ws + 104857600ull);      // 16 KB     fp32
  float* ctab= (float*)(ws + 104874368ull);      //  2 KB
  float* stab= (float*)(ws + 104876416ull);      //  2 KB
  u16* kvbT  = (u16*)(ws + 104878464ull);        // 0.5 MB    kv^T bf16
  // kv partials (16.7 MB) + ksump (256 KB) live in d_out scratch;
  // attn overwrites all of out afterwards (stream-ordered).
  float* partial = out;
  float* ksump   = out + 4194304;

  hipLaunchKernelGGL(cast_kernel, dim3(2050), dim3(256), 0, stream, x, Wqk, xb, wb, ctab, stab);
  hipLaunchKernelGGL(gemm_kernel, dim3(64, 8), dim3(512), 0, stream, xb, wb, bqk, ctab, stab, qrb, krb);
  hipLaunchKernelGGL(kvpart_kernel, dim3(1024), dim3(256), 0, stream, krb, xb, partial, ksump);
  hipLaunchKernelGGL(kvred_kernel, dim3(64), dim3(256), 0, stream, partial, ksump, kvbT, kmr);
  hipLaunchKernelGGL(attn_kernel, dim3(32, 16, 4), dim3(256), 0, stream, qrb, kvbT, kmr, xb, lw, lb, out);
}